// Round 8
// baseline (942.170 us; speedup 1.0000x reference)
//
#include <hip/hip_runtime.h>

#define F 576
#define OUTC 256
#define SNUM 64
#define PP 576.0f
#define NBLK 36
#define FLAG_STRIDE 32   // 128 B between per-block flags (one MALL line each)

// ---------------- device barrier: per-block flags + master aggregator ----------------
// No same-line RMW contention: each block stores to its own line; block 0 polls all
// flags then publishes gen; spinners poll gen (concurrent reads, no serialization).
// One release-fence (wbL2) before flag store, one acquire-fence (inv) at exit.
__device__ __forceinline__ void gbar(int* flags, int* gen, int b, int barid) {
  __syncthreads();
  if (threadIdx.x == 0) {
    __builtin_amdgcn_fence(__ATOMIC_RELEASE, "agent");
    __hip_atomic_store(&flags[b * FLAG_STRIDE], barid, __ATOMIC_RELAXED, __HIP_MEMORY_SCOPE_AGENT);
    if (b == 0) {
      for (int i = 1; i < NBLK; ++i) {
        while (__hip_atomic_load(&flags[i * FLAG_STRIDE], __ATOMIC_RELAXED, __HIP_MEMORY_SCOPE_AGENT) < barid) {
          __builtin_amdgcn_s_sleep(1);
        }
      }
      __hip_atomic_store(gen, barid, __ATOMIC_RELAXED, __HIP_MEMORY_SCOPE_AGENT);
    } else {
      while (__hip_atomic_load(gen, __ATOMIC_RELAXED, __HIP_MEMORY_SCOPE_AGENT) < barid) {
        __builtin_amdgcn_s_sleep(1);
      }
    }
    __builtin_amdgcn_fence(__ATOMIC_ACQUIRE, "agent");
  }
  __syncthreads();
}

// ---------------- shared inner product (proven core) ----------------
__device__ __forceinline__ void mm16(const float (*As)[68], const float (*Bs)[68],
                                     float acc[4][4], int tx, int ty) {
#pragma unroll
  for (int k = 0; k < 32; ++k) {
    float4 a4 = *(const float4*)&As[k][ty * 4];
    float4 b4 = *(const float4*)&Bs[k][tx * 4];
    float av[4] = {a4.x, a4.y, a4.z, a4.w};
    float bv[4] = {b4.x, b4.y, b4.z, b4.w};
#pragma unroll
    for (int r = 0; r < 4; ++r)
#pragma unroll
      for (int c = 0; c < 4; ++c) acc[r][c] += av[r] * bv[c];
  }
}

// ---------------- generic 64x64 tile of C = sgn * A@B ----------------
__device__ void tile_gemm(const float* __restrict__ A, int lda,
                          const float* __restrict__ B, int ldb,
                          float* __restrict__ C, int ldc,
                          int m0, int n0, int K, float sgn,
                          float (*As)[68], float (*Bs)[68]) {
  int t = threadIdx.x, tx = t & 15, ty = t >> 4;
  float acc[4][4] = {};
  for (int k0 = 0; k0 < K; k0 += 32) {
    int rr = t >> 2, kq = t & 3;
    const float* ap = &A[(m0 + rr) * lda + k0 + kq * 8];
    float4 a0 = *(const float4*)ap;
    float4 a1 = *(const float4*)(ap + 4);
    As[kq*8+0][rr] = a0.x; As[kq*8+1][rr] = a0.y;
    As[kq*8+2][rr] = a0.z; As[kq*8+3][rr] = a0.w;
    As[kq*8+4][rr] = a1.x; As[kq*8+5][rr] = a1.y;
    As[kq*8+6][rr] = a1.z; As[kq*8+7][rr] = a1.w;
    int col = t & 63, kr = t >> 6;
#pragma unroll
    for (int kk = 0; kk < 32; kk += 4)
      Bs[kr + kk][col] = B[(k0 + kr + kk) * ldb + n0 + col];
    __syncthreads();
    mm16(As, Bs, acc, tx, ty);
    __syncthreads();
  }
#pragma unroll
  for (int r = 0; r < 4; ++r)
#pragma unroll
    for (int c = 0; c < 4; ++c)
      C[(m0 + ty*4 + r) * ldc + n0 + tx*4 + c] = sgn * acc[r][c];
}

// ---------------- serial 64x64 Cholesky on LDS tile (wave 0) ----------------
__device__ void diag_factor(float* Ts /* 64x66 */) {
  int t = threadIdx.x;
  __syncthreads();
  if (t < 64) {
    int l = t;
    float r[64];
#pragma unroll
    for (int g = 0; g < 64; ++g) r[g] = Ts[l*66 + g];
#pragma unroll
    for (int j = 0; j < 64; ++j) {
      float d = __shfl(r[j], j, 64);
      float inv = 1.0f / sqrtf(d);
      float c = r[j] * inv;
      r[j] = c;
#pragma unroll
      for (int g = j + 1; g < 64; ++g)
        r[g] = fmaf(-__shfl(c, g, 64), c, r[g]);
    }
#pragma unroll
    for (int g = 0; g < 64; ++g) Ts[l*66 + g] = r[g];
  }
  __syncthreads();
}

// ---------------- panel solve: 16 rows per block (4 waves x 4 rows) ----------------
__device__ void panel_phase(float* __restrict__ G, int k0, int b,
                            float* Ts, float* invd) {
  int t = threadIdx.x;
  for (int idx = t; idx < 64 * 64; idx += 256) {
    int i = idx >> 6, j = idx & 63;
    Ts[i*66 + j] = G[(k0 + i) * F + k0 + j];
  }
  __syncthreads();
  if (t < 64) invd[t] = 1.0f / Ts[t*66 + t];
  __syncthreads();
  int l = t & 63, w = t >> 6;
  int r0 = k0 + 64 + b * 16 + w * 4;
  float v0 = G[(r0 + 0) * F + k0 + l];
  float v1 = G[(r0 + 1) * F + k0 + l];
  float v2 = G[(r0 + 2) * F + k0 + l];
  float v3 = G[(r0 + 3) * F + k0 + l];
#pragma unroll
  for (int j = 0; j < 64; ++j) {
    float dj = invd[j];
    float x0 = __shfl(v0, j, 64) * dj;
    float x1 = __shfl(v1, j, 64) * dj;
    float x2 = __shfl(v2, j, 64) * dj;
    float x3 = __shfl(v3, j, 64) * dj;
    if (l > j) {
      float lj = Ts[l*66 + j];
      v0 = fmaf(-x0, lj, v0);
      v1 = fmaf(-x1, lj, v1);
      v2 = fmaf(-x2, lj, v2);
      v3 = fmaf(-x3, lj, v3);
    }
  }
  float dl = invd[l];
  G[(r0 + 0) * F + k0 + l] = v0 * dl;
  G[(r0 + 1) * F + k0 + l] = v1 * dl;
  G[(r0 + 2) * F + k0 + l] = v2 * dl;
  G[(r0 + 3) * F + k0 + l] = v3 * dl;
}

// ---------------- rank-64 trailing update tile (+ fused next-diag for tile (0,0)) ----------------
__device__ void upd_phase(float* __restrict__ G, int k0, int ti, int tj, bool fuse,
                          float (*As)[68], float (*Bs)[68], float* Ts) {
  int b0 = k0 + 64;
  int i0 = b0 + ti * 64, j0 = b0 + tj * 64;
  int t = threadIdx.x, tx = t & 15, ty = t >> 4;
  float acc[4][4] = {};
  for (int kk0 = 0; kk0 < 64; kk0 += 32) {
    for (int idx = t; idx < 64 * 32; idx += 256) {
      int ii = idx >> 5, kk = idx & 31;
      As[kk][ii] = G[(i0 + ii) * F + k0 + kk0 + kk];
      Bs[kk][ii] = G[(j0 + ii) * F + k0 + kk0 + kk];
    }
    __syncthreads();
#pragma unroll
    for (int k = 0; k < 32; ++k) {
      float a[4], b[4];
#pragma unroll
      for (int m = 0; m < 4; ++m) { a[m] = As[k][ty*4 + m]; b[m] = Bs[k][tx*4 + m]; }
#pragma unroll
      for (int r = 0; r < 4; ++r)
#pragma unroll
        for (int c = 0; c < 4; ++c) acc[r][c] += a[r] * b[c];
    }
    __syncthreads();
  }
  if (!fuse) {
#pragma unroll
    for (int r = 0; r < 4; ++r)
#pragma unroll
      for (int c = 0; c < 4; ++c)
        G[(i0 + ty*4 + r) * F + j0 + tx*4 + c] -= acc[r][c];
  } else {
#pragma unroll
    for (int r = 0; r < 4; ++r)
#pragma unroll
      for (int c = 0; c < 4; ++c)
        Ts[(ty*4 + r)*66 + tx*4 + c] =
            G[(i0 + ty*4 + r) * F + j0 + tx*4 + c] - acc[r][c];
    diag_factor(Ts);
    for (int idx = t; idx < 64 * 64; idx += 256) {
      int i = idx >> 6, j = idx & 63;
      if (j <= i) G[(i0 + i) * F + j0 + j] = Ts[i*66 + j];
    }
  }
}

// ---------------- invert diagonal 64x64 triangular block -> LI ----------------
__device__ void base_inv_phase(const float* __restrict__ G, float* __restrict__ LI,
                               int blk, float* Ts, float* invd) {
  int base = blk * 64, t = threadIdx.x;
  for (int idx = t; idx < 64 * 64; idx += 256) {
    int i = idx >> 6, j = idx & 63;
    Ts[i*66 + j] = G[(base + i) * F + base + j];
  }
  __syncthreads();
  if (t < 64) invd[t] = 1.0f / Ts[t*66 + t];
  __syncthreads();
  int l = t & 63, w = t >> 6;
  float v[16];
#pragma unroll
  for (int c = 0; c < 16; ++c) v[c] = (l == (w * 16 + c)) ? 1.0f : 0.0f;
#pragma unroll
  for (int j = 0; j < 64; ++j) {
    float dj = invd[j];
    float lj = (l > j) ? Ts[l*66 + j] : 0.0f;
#pragma unroll
    for (int c = 0; c < 16; ++c) {
      float x = __shfl(v[c], j, 64) * dj;
      v[c] = fmaf(-x, lj, v[c]);
    }
  }
  float dl = invd[l];
#pragma unroll
  for (int c = 0; c < 16; ++c)
    LI[(base + l) * F + base + w * 16 + c] = v[c] * dl;
}

// ---------------- meanT[o][f] = sum_g LI[g][f] T[g][o] ----------------
__device__ void mean_phase(const float* __restrict__ LI, const float* __restrict__ T,
                           float* __restrict__ meanT, int bf, int bo,
                           float (*As)[68], float (*Bs)[68]) {
  int t = threadIdx.x, tx = t & 15, ty = t >> 4;
  int f0 = bf * 64, o0 = bo * 64;
  float acc[4][4] = {};
  for (int g0 = f0; g0 < F; g0 += 32) {
    int col = t & 63, kr = t >> 6;
#pragma unroll
    for (int kk = 0; kk < 32; kk += 4) {
      As[kr + kk][col] = T[(g0 + kr + kk) * OUTC + o0 + col];
      Bs[kr + kk][col] = LI[(g0 + kr + kk) * F + f0 + col];
    }
    __syncthreads();
    mm16(As, Bs, acc, tx, ty);
    __syncthreads();
  }
#pragma unroll
  for (int r = 0; r < 4; ++r) {
    float4 st = make_float4(acc[r][0], acc[r][1], acc[r][2], acc[r][3]);
    *(float4*)&meanT[(o0 + ty*4 + r) * F + f0 + tx*4] = st;
  }
}

// ================= k_mid: Cholesky + inversion + gemm_T + gemm_mean, one launch =================
__global__ __launch_bounds__(256) void k_mid(float* __restrict__ G, float* __restrict__ LI,
                                             const float* __restrict__ Yb,
                                             float* __restrict__ Tb, float* __restrict__ meanT,
                                             int* __restrict__ gen, int* __restrict__ flags) {
  __shared__ float As[32][68];
  __shared__ float Bs[32][68];
  __shared__ float Ts[64 * 66];
  __shared__ float invd[64];
  int bar = 0;
  int b = blockIdx.x, t = threadIdx.x;
  float* Tw = Tb;   // trigemm temp; consumed before Tb written by gemm_T phase

  // ---- diag k=0 ----
  if (b == 0) {
    for (int idx = t; idx < 64 * 64; idx += 256) {
      int i = idx >> 6, j = idx & 63;
      Ts[i*66 + j] = G[i * F + j];
    }
    diag_factor(Ts);
    for (int idx = t; idx < 64 * 64; idx += 256) {
      int i = idx >> 6, j = idx & 63;
      if (j <= i) G[i * F + j] = Ts[i*66 + j];
    }
  }
  gbar(flags, gen, b, ++bar);

  // ---- blocked right-looking Cholesky, diag(k+1) fused into upd(k) ----
  for (int k = 0; k < 8; ++k) {
    int k0 = k * 64;
    int n = 512 - k0;            // rows below current diag
    if (b < n / 16) panel_phase(G, k0, b, Ts, invd);
    gbar(flags, gen, b, ++bar);
    int nt = n / 64, ntiles = nt * (nt + 1) / 2;
    if (b < ntiles) {
      int ti = 0, bb = b;
      while (bb >= ti + 1) { bb -= ti + 1; ++ti; }
      int tj = bb;
      upd_phase(G, k0, ti, tj, (ti == 0 && tj == 0), As, Bs, Ts);
    }
    gbar(flags, gen, b, ++bar);
  }

  // ---- base inversions + zero off-diagonal LI blocks ----
  if (b < 9) {
    base_inv_phase(G, LI, b, Ts, invd);
  } else {
    int m = b - 9;
    for (int q = m; q < 72; q += 27) {
      int r = q / 8, cc = q % 8;
      int c = cc + (cc >= r ? 1 : 0);
      for (int idx = t; idx < 64 * 16; idx += 256) {
        int i = idx >> 4, jj = idx & 15;
        ((float4*)&LI[(r * 64 + i) * F + c * 64])[jj] = make_float4(0.f, 0.f, 0.f, 0.f);
      }
    }
  }
  gbar(flags, gen, b, ++bar);

  // ---- recursive triangular inverse levels (576 = 512 + 64) ----
  // L1: 4 pairs n=64 — producer block == consumer block, merged (no barrier inside)
  if (b < 4) {
    tile_gemm(G + 64*F + b*128*(F+1), F, LI + b*128*(F+1), F,
              Tw + b*4096, 64, 0, 0, 64, 1.0f, As, Bs);
    tile_gemm(LI + 64*(F+1) + b*128*(F+1), F, Tw + b*4096, 64,
              LI + 64*F + b*128*(F+1), F, 0, 0, 64, -1.0f, As, Bs);
  }
  gbar(flags, gen, b, ++bar);
  // L2: 2 pairs n=128
  if (b < 8) {
    int z = b >> 2, tl = b & 3;
    tile_gemm(G + 128*F + z*256*(F+1), F, LI + z*256*(F+1), F,
              Tw + z*16384, 128, (tl>>1)*64, (tl&1)*64, 128, 1.0f, As, Bs);
  }
  gbar(flags, gen, b, ++bar);
  if (b < 8) {
    int z = b >> 2, tl = b & 3;
    tile_gemm(LI + 128*(F+1) + z*256*(F+1), F, Tw + z*16384, 128,
              LI + 128*F + z*256*(F+1), F, (tl>>1)*64, (tl&1)*64, 128, -1.0f, As, Bs);
  }
  gbar(flags, gen, b, ++bar);
  // L3: 1 pair n=256
  if (b < 16) tile_gemm(G + 256*F, F, LI, F, Tw, 256,
                        (b>>2)*64, (b&3)*64, 256, 1.0f, As, Bs);
  gbar(flags, gen, b, ++bar);
  if (b < 16) tile_gemm(LI + 256*(F+1), F, Tw, 256, LI + 256*F, F,
                        (b>>2)*64, (b&3)*64, 256, -1.0f, As, Bs);
  gbar(flags, gen, b, ++bar);
  // L4: 512 + 64 — producer tile == consumer tile per block, merged
  if (b < 8) {
    tile_gemm(G + 512*F, F, LI, F, Tw, 512, 0, b*64, 512, 1.0f, As, Bs);
    tile_gemm(LI + 512*(F+1), F, Tw, 512, LI + 512*F, F, 0, b*64, 64, -1.0f, As, Bs);
  }
  gbar(flags, gen, b, ++bar);

  // ---- gemm_T: Tb[g][o] = sum_h LI[g][h] Yb[h][o]  (K = g0+64, triangular) ----
  {
    int bg = b >> 2, bo = b & 3;
    tile_gemm(LI, F, Yb, OUTC, Tb, OUTC, bg * 64, bo * 64, bg * 64 + 64, 1.0f, As, Bs);
  }
  gbar(flags, gen, b, ++bar);

  // ---- gemm_mean ----
  {
    int bf = b >> 2, bo = b & 3;
    mean_phase(LI, Tb, meanT, bf, bo, As, Bs);
  }
}

// ================= k_gy: G and Y builds merged (z-split) =================
__global__ __launch_bounds__(256) void k_gy(const float* __restrict__ X,
                                            const float* __restrict__ u,
                                            const float* __restrict__ lp,
                                            float* __restrict__ G,
                                            float* __restrict__ Y) {
  __shared__ float As[32][68];
  __shared__ float Bs[32][68];
  int t = threadIdx.x, tx = t & 15, ty = t >> 4;
  if (blockIdx.z == 0) {
    int bi = blockIdx.y, bj = blockIdx.x;
    if (bj > bi) return;
    int f0 = bi * 64, g0 = bj * 64;
    float acc[4][4] = {};
    for (int i0 = 0; i0 < F; i0 += 32) {
      int col = t & 63, kr = t >> 6;
#pragma unroll
      for (int kk = 0; kk < 32; kk += 4) {
        int i = i0 + kr + kk;
        float e = expf(lp[i]);
        As[kr + kk][col] = e * X[i * F + f0 + col];
        Bs[kr + kk][col] = X[i * F + g0 + col];
      }
      __syncthreads();
      mm16(As, Bs, acc, tx, ty);
      __syncthreads();
    }
#pragma unroll
    for (int r = 0; r < 4; ++r) {
      int gr = f0 + ty*4 + r;
#pragma unroll
      for (int c = 0; c < 4; ++c) {
        int gc = g0 + tx*4 + c;
        float v = acc[r][c];
        if (gr == gc) v += PP;
        G[gr * F + gc] = v;
      }
    }
  } else {
    if (blockIdx.x >= 4) return;
    int bo = blockIdx.x, bf = blockIdx.y;
    int f0 = bf * 64, o0 = bo * 64;
    float acc[4][4] = {};
    for (int i0 = 0; i0 < F; i0 += 32) {
      {
        int col = t & 63, kr = t >> 6;
#pragma unroll
        for (int kk = 0; kk < 32; kk += 4) {
          int i = i0 + kr + kk;
          As[kr + kk][col] = expf(lp[i]) * X[i * F + f0 + col];
        }
        int oo = t >> 2, kq = t & 3;
        const float* ur = &u[(o0 + oo) * F + i0 + kq * 8];
        float4 u0 = *(const float4*)ur;
        float4 u1 = *(const float4*)(ur + 4);
        Bs[kq*8+0][oo] = u0.x; Bs[kq*8+1][oo] = u0.y;
        Bs[kq*8+2][oo] = u0.z; Bs[kq*8+3][oo] = u0.w;
        Bs[kq*8+4][oo] = u1.x; Bs[kq*8+5][oo] = u1.y;
        Bs[kq*8+6][oo] = u1.z; Bs[kq*8+7][oo] = u1.w;
      }
      __syncthreads();
      mm16(As, Bs, acc, tx, ty);
      __syncthreads();
    }
#pragma unroll
    for (int r = 0; r < 4; ++r) {
      float4 st = make_float4(acc[r][0], acc[r][1], acc[r][2], acc[r][3]);
      *(float4*)&Y[(f0 + ty*4 + r) * OUTC + o0 + tx*4] = st;
    }
  }
}

// ================= k_big: out = Z@Linv + mean, fused f64 logpq partials =================
__global__ __launch_bounds__(256) void k_big(const float* __restrict__ Z,
                                             const float* __restrict__ LI,
                                             const float* __restrict__ meanT,
                                             float* __restrict__ out,
                                             double* __restrict__ parts) {
  int bf = blockIdx.x, br = blockIdx.y;
  __shared__ float As[32][68];
  __shared__ float Bs[32][68];
  __shared__ double redA[256];
  __shared__ double redB[256];
  int t = threadIdx.x, tx = t & 15, ty = t >> 4;
  int f0 = bf * 64, r0 = br * 64;
  float acc[4][4] = {};
  double zsq = 0.0;
  for (int g0 = f0; g0 < F; g0 += 32) {
    {
      int rr = t >> 2, kq = t & 3;
      const float* zr = &Z[(r0 + rr) * F + g0 + kq * 8];
      float4 a0 = *(const float4*)zr;
      float4 a1 = *(const float4*)(zr + 4);
      if (bf == 0) {
        zsq += (double)a0.x*a0.x + (double)a0.y*a0.y + (double)a0.z*a0.z + (double)a0.w*a0.w
             + (double)a1.x*a1.x + (double)a1.y*a1.y + (double)a1.z*a1.z + (double)a1.w*a1.w;
      }
      As[kq*8+0][rr] = a0.x; As[kq*8+1][rr] = a0.y;
      As[kq*8+2][rr] = a0.z; As[kq*8+3][rr] = a0.w;
      As[kq*8+4][rr] = a1.x; As[kq*8+5][rr] = a1.y;
      As[kq*8+6][rr] = a1.z; As[kq*8+7][rr] = a1.w;
      int col = t & 63, kr = t >> 6;
#pragma unroll
      for (int kk = 0; kk < 32; kk += 4)
        Bs[kr + kk][col] = LI[(g0 + kr + kk) * F + f0 + col];
    }
    __syncthreads();
    mm16(As, Bs, acc, tx, ty);
    __syncthreads();
  }
  double ssq = 0.0;
#pragma unroll
  for (int r = 0; r < 4; ++r) {
    int row = r0 + ty*4 + r;
    int o = row & 255;
    float4 mv = *(const float4*)&meanT[o * F + f0 + tx*4];
    float4 st = make_float4(acc[r][0] + mv.x, acc[r][1] + mv.y,
                            acc[r][2] + mv.z, acc[r][3] + mv.w);
    *(float4*)&out[row * F + f0 + tx*4] = st;
    ssq += (double)st.x*st.x + (double)st.y*st.y + (double)st.z*st.z + (double)st.w*st.w;
  }
  redA[t] = ssq; redB[t] = zsq;
  __syncthreads();
  for (int o = 128; o > 0; o >>= 1) {
    if (t < o) { redA[t] += redA[t + o]; redB[t] += redB[t + o]; }
    __syncthreads();
  }
  if (t == 0) {
    int s = br >> 2;
    atomicAdd(&parts[s * 2 + 0], redA[0]);
    if (bf == 0) atomicAdd(&parts[s * 2 + 1], redB[0]);
  }
}

// ================= logpq final =================
__global__ __launch_bounds__(576) void k_logpq_final(const float* __restrict__ LI,
                                                     const double* __restrict__ parts,
                                                     float* __restrict__ out) {
  __shared__ double red[576];
  int t = threadIdx.x;
  red[t] = log((double)LI[t * F + t]);   // = -log(L[t][t])
  __syncthreads();
  for (int o = 512; o > 0; o >>= 1) {
    if (t < o && t + o < 576) red[t] += red[t + o];
    __syncthreads();
  }
  double ldsumLI = red[0];
  if (t < SNUM) {
    double ssq = parts[t * 2 + 0];
    double zsq = parts[t * 2 + 1];
    double pp = 576.0;
    double lpq = -0.5 * pp * ssq
               + 0.5 * (double)(OUTC * F) * log(pp)
               + 0.5 * zsq
               + (double)OUTC * ldsumLI;
    out[SNUM * OUTC * F + t] = (float)lpq;
  }
}

// ================= launch =================
extern "C" void kernel_launch(void* const* d_in, const int* in_sizes, int n_in,
                              void* d_out, int out_size, void* d_ws, size_t ws_size,
                              hipStream_t stream) {
  (void)in_sizes; (void)n_in; (void)out_size; (void)ws_size;
  const float* X  = (const float*)d_in[1];   // Xi_param [1,576,576]
  const float* u  = (const float*)d_in[2];   // u [256,576,1]
  const float* lp = (const float*)d_in[3];   // log_prec_scaled [1,1,576]
  const float* Z  = (const float*)d_in[4];   // Z [64,256,576,1]
  float* out = (float*)d_out;

  float* ws    = (float*)d_ws;
  float* G     = ws;                   // 331776
  float* LI    = ws + 331776;          // 331776
  float* Yb    = ws + 663552;          // 147456
  float* Tb    = ws + 811008;          // 147456 (also trigemm temp)
  float* meanT = ws + 958464;          // 147456
  double* parts = (double*)(ws + 1105920);        // 128 doubles (1024 B)
  int*    gen   = (int*)(ws + 1105920 + 256);     // 1 int (own line)
  int*    flags = (int*)(ws + 1105920 + 288);     // 36 * 32 ints (128 B apart)

  hipMemsetAsync((void*)(ws + 1105920), 0, 8192, stream);  // parts + gen + flags
  k_gy<<<dim3(9, 9, 2), 256, 0, stream>>>(X, u, lp, G, Yb);
  k_mid<<<NBLK, 256, 0, stream>>>(G, LI, Yb, Tb, meanT, gen, flags);
  k_big<<<dim3(9, 256), 256, 0, stream>>>(Z, LI, meanT, out, parts);
  k_logpq_final<<<1, 576, 0, stream>>>(LI, parts, out);
}

// Round 9
// 797.922 us; speedup vs baseline: 1.1808x; 1.1808x over previous
//
#include <hip/hip_runtime.h>

#define F 576
#define OUTC 256
#define SNUM 64
#define PP 576.0f
#define NBLK 36

// ---------------- device barrier (round-7 best: single counter, hoisted fences) ----------------
__device__ __forceinline__ void gbar(int* cnt, int barid) {
  __syncthreads();
  if (threadIdx.x == 0) {
    __builtin_amdgcn_fence(__ATOMIC_RELEASE, "agent");
    __hip_atomic_fetch_add(cnt, 1, __ATOMIC_RELAXED, __HIP_MEMORY_SCOPE_AGENT);
    int target = barid * NBLK;
    while (__hip_atomic_load(cnt, __ATOMIC_RELAXED, __HIP_MEMORY_SCOPE_AGENT) < target) {
      __builtin_amdgcn_s_sleep(2);
    }
    __builtin_amdgcn_fence(__ATOMIC_ACQUIRE, "agent");
  }
  __syncthreads();
}

// ---------------- shared inner product (proven core) ----------------
__device__ __forceinline__ void mm16(const float (*As)[68], const float (*Bs)[68],
                                     float acc[4][4], int tx, int ty) {
#pragma unroll
  for (int k = 0; k < 32; ++k) {
    float4 a4 = *(const float4*)&As[k][ty * 4];
    float4 b4 = *(const float4*)&Bs[k][tx * 4];
    float av[4] = {a4.x, a4.y, a4.z, a4.w};
    float bv[4] = {b4.x, b4.y, b4.z, b4.w};
#pragma unroll
    for (int r = 0; r < 4; ++r)
#pragma unroll
      for (int c = 0; c < 4; ++c) acc[r][c] += av[r] * bv[c];
  }
}

// ---------------- solve micro-GEMM: acc[r4] += sum_k As[k][ty4+m] * Xs[k][tx] ----------------
__device__ __forceinline__ void mmqs(const float (*As)[68], const float (*Xs)[20],
                                     float acc[4], int tx, int ty) {
#pragma unroll
  for (int k = 0; k < 32; ++k) {
    float4 a4 = *(const float4*)&As[k][ty * 4];
    float b = Xs[k][tx];
    acc[0] += a4.x * b; acc[1] += a4.y * b;
    acc[2] += a4.z * b; acc[3] += a4.w * b;
  }
}

// As[k][r] = M[r][h*32+k]  (transpose-stage, 64 rows x 32 k)
__device__ __forceinline__ void stageA_T(const float* __restrict__ M, int lda, int h,
                                         float (*As)[68]) {
  int t = threadIdx.x, rr = t >> 2, kq = t & 3;
  const float* ap = &M[rr * lda + h * 32 + kq * 8];
  float4 a0 = *(const float4*)ap;
  float4 a1 = *(const float4*)(ap + 4);
  As[kq*8+0][rr] = a0.x; As[kq*8+1][rr] = a0.y;
  As[kq*8+2][rr] = a0.z; As[kq*8+3][rr] = a0.w;
  As[kq*8+4][rr] = a1.x; As[kq*8+5][rr] = a1.y;
  As[kq*8+6][rr] = a1.z; As[kq*8+7][rr] = a1.w;
}

// As[k][r] = M[h*32+k][r]  (natural-stage)
__device__ __forceinline__ void stageA_N(const float* __restrict__ M, int lda, int h,
                                         float (*As)[68]) {
  int t = threadIdx.x, col = t & 63, kr = t >> 6;
#pragma unroll
  for (int kk = 0; kk < 32; kk += 4)
    As[kr + kk][col] = M[(h * 32 + kr + kk) * lda + col];
}

// Xs[k][c] = src[(h*32+k)*ldx + c0 + c]   (32 x 16)
__device__ __forceinline__ void stageX(const float* __restrict__ src, int ldx, int c0, int h,
                                       float (*Xs)[20]) {
  int t = threadIdx.x, k = t >> 3, c = (t & 7) * 2;
  Xs[k][c]     = src[(h * 32 + k) * ldx + c0 + c];
  Xs[k][c + 1] = src[(h * 32 + k) * ldx + c0 + c + 1];
}

// Xs[k][c] = src[(c0+c)*ldsrc + poff + h*32 + k]   (transposed source)
__device__ __forceinline__ void stageX_T(const float* __restrict__ src, int ldsrc, int c0,
                                         int poff, int h, float (*Xs)[20]) {
  int t = threadIdx.x, k = t >> 3, c = (t & 7) * 2;
  Xs[k][c]     = src[(c0 + c) * ldsrc + poff + h * 32 + k];
  Xs[k][c + 1] = src[(c0 + c + 1) * ldsrc + poff + h * 32 + k];
}

// ---------------- LI block-col solve: LI[:,j-col,q-quarter], forward substitution ----------------
__device__ void solve_LI(const float* __restrict__ G, float* __restrict__ LI,
                         int j, int q, float (*As)[68], float (*Xs)[20]) {
  int t = threadIdx.x, tx = t & 15, ty = t >> 4;
  int c0 = j * 64 + q * 16;
  for (int i = j + 1; i <= 8; ++i) {
    float acc[4] = {0.f, 0.f, 0.f, 0.f};
    for (int p = j; p < i; ++p)
      for (int h = 0; h < 2; ++h) {
        __syncthreads();
        stageA_T(&G[(i * 64) * F + p * 64], F, h, As);
        stageX(&LI[(p * 64) * F], F, c0, h, Xs);
        __syncthreads();
        mmqs(As, Xs, acc, tx, ty);
      }
    float out[4] = {0.f, 0.f, 0.f, 0.f};
    for (int h = 0; h < 2; ++h) {
      __syncthreads();
      if ((ty >> 3) == h) {
        int rl = (ty & 7) * 4;
        Xs[rl+0][tx] = -acc[0]; Xs[rl+1][tx] = -acc[1];
        Xs[rl+2][tx] = -acc[2]; Xs[rl+3][tx] = -acc[3];
      }
      stageA_T(&LI[(i * 64) * F + i * 64], F, h, As);
      __syncthreads();
      mmqs(As, Xs, out, tx, ty);
    }
#pragma unroll
    for (int m = 0; m < 4; ++m)
      LI[(i * 64 + ty * 4 + m) * F + c0 + tx] = out[m];
  }
}

// ---------------- T = L^{-1} Yb, RHS quarter q16 ----------------
__device__ void solve_T(const float* __restrict__ G, const float* __restrict__ LI,
                        const float* __restrict__ Yb, float* __restrict__ Tb,
                        int q16, float (*As)[68], float (*Xs)[20]) {
  int t = threadIdx.x, tx = t & 15, ty = t >> 4;
  int c0 = q16 * 16;
  for (int i = 0; i <= 8; ++i) {
    float acc[4] = {0.f, 0.f, 0.f, 0.f};
    for (int p = 0; p < i; ++p)
      for (int h = 0; h < 2; ++h) {
        __syncthreads();
        stageA_T(&G[(i * 64) * F + p * 64], F, h, As);
        stageX(&Tb[(p * 64) * OUTC], OUTC, c0, h, Xs);
        __syncthreads();
        mmqs(As, Xs, acc, tx, ty);
      }
    float out[4] = {0.f, 0.f, 0.f, 0.f};
    for (int h = 0; h < 2; ++h) {
      __syncthreads();
      if ((ty >> 3) == h) {
        int rl = (ty & 7) * 4;
#pragma unroll
        for (int m = 0; m < 4; ++m)
          Xs[rl + m][tx] = Yb[(i * 64 + h * 32 + rl + m) * OUTC + c0 + tx] - acc[m];
      }
      stageA_T(&LI[(i * 64) * F + i * 64], F, h, As);
      __syncthreads();
      mmqs(As, Xs, out, tx, ty);
    }
#pragma unroll
    for (int m = 0; m < 4; ++m)
      Tb[(i * 64 + ty * 4 + m) * OUTC + c0 + tx] = out[m];
  }
}

// ---------------- meanT = (L^{-T} T)^T: backward substitution, writes meanT[o][f] ----------------
__device__ void solve_M(const float* __restrict__ G, const float* __restrict__ LI,
                        const float* __restrict__ Tb, float* __restrict__ meanT,
                        int q16, float (*As)[68], float (*Xs)[20]) {
  int t = threadIdx.x, tx = t & 15, ty = t >> 4;
  int c0 = q16 * 16;
  for (int i = 8; i >= 0; --i) {
    float acc[4] = {0.f, 0.f, 0.f, 0.f};
    for (int p = i + 1; p <= 8; ++p)
      for (int h = 0; h < 2; ++h) {
        __syncthreads();
        stageA_N(&G[(p * 64) * F + i * 64], F, h, As);     // (L_pi^T)[r][k]
        stageX_T(meanT, F, c0, p * 64, h, Xs);             // M_p[k][c]
        __syncthreads();
        mmqs(As, Xs, acc, tx, ty);
      }
    float out[4] = {0.f, 0.f, 0.f, 0.f};
    for (int h = 0; h < 2; ++h) {
      __syncthreads();
      if ((ty >> 3) == h) {
        int rl = (ty & 7) * 4;
#pragma unroll
        for (int m = 0; m < 4; ++m)
          Xs[rl + m][tx] = Tb[(i * 64 + h * 32 + rl + m) * OUTC + c0 + tx] - acc[m];
      }
      stageA_N(&LI[(i * 64) * F + i * 64], F, h, As);      // Linv_ii^T
      __syncthreads();
      mmqs(As, Xs, out, tx, ty);
    }
    float4 st = make_float4(out[0], out[1], out[2], out[3]);
    *(float4*)&meanT[(c0 + tx) * F + i * 64 + ty * 4] = st;
  }
}

// ---------------- serial 64x64 Cholesky on LDS tile (wave 0) ----------------
__device__ void diag_factor(float* Ts /* 64x66 */) {
  int t = threadIdx.x;
  __syncthreads();
  if (t < 64) {
    int l = t;
    float r[64];
#pragma unroll
    for (int g = 0; g < 64; ++g) r[g] = Ts[l*66 + g];
#pragma unroll
    for (int j = 0; j < 64; ++j) {
      float d = __shfl(r[j], j, 64);
      float inv = 1.0f / sqrtf(d);
      float c = r[j] * inv;
      r[j] = c;
#pragma unroll
      for (int g = j + 1; g < 64; ++g)
        r[g] = fmaf(-__shfl(c, g, 64), c, r[g]);
    }
#pragma unroll
    for (int g = 0; g < 64; ++g) Ts[l*66 + g] = r[g];
  }
  __syncthreads();
}

// ---------------- panel solve: 16 rows per block ----------------
__device__ void panel_phase(float* __restrict__ G, int k0, int b,
                            float* Ts, float* invd) {
  int t = threadIdx.x;
  for (int idx = t; idx < 64 * 64; idx += 256) {
    int i = idx >> 6, j = idx & 63;
    Ts[i*66 + j] = G[(k0 + i) * F + k0 + j];
  }
  __syncthreads();
  if (t < 64) invd[t] = 1.0f / Ts[t*66 + t];
  __syncthreads();
  int l = t & 63, w = t >> 6;
  int r0 = k0 + 64 + b * 16 + w * 4;
  float v0 = G[(r0 + 0) * F + k0 + l];
  float v1 = G[(r0 + 1) * F + k0 + l];
  float v2 = G[(r0 + 2) * F + k0 + l];
  float v3 = G[(r0 + 3) * F + k0 + l];
#pragma unroll
  for (int j = 0; j < 64; ++j) {
    float dj = invd[j];
    float x0 = __shfl(v0, j, 64) * dj;
    float x1 = __shfl(v1, j, 64) * dj;
    float x2 = __shfl(v2, j, 64) * dj;
    float x3 = __shfl(v3, j, 64) * dj;
    if (l > j) {
      float lj = Ts[l*66 + j];
      v0 = fmaf(-x0, lj, v0);
      v1 = fmaf(-x1, lj, v1);
      v2 = fmaf(-x2, lj, v2);
      v3 = fmaf(-x3, lj, v3);
    }
  }
  float dl = invd[l];
  G[(r0 + 0) * F + k0 + l] = v0 * dl;
  G[(r0 + 1) * F + k0 + l] = v1 * dl;
  G[(r0 + 2) * F + k0 + l] = v2 * dl;
  G[(r0 + 3) * F + k0 + l] = v3 * dl;
}

// ---------------- rank-64 trailing update tile (+ fused next-diag at (0,0)) ----------------
__device__ void upd_phase(float* __restrict__ G, int k0, int ti, int tj, bool fuse,
                          float (*As)[68], float (*Bs)[68], float* Ts) {
  int b0 = k0 + 64;
  int i0 = b0 + ti * 64, j0 = b0 + tj * 64;
  int t = threadIdx.x, tx = t & 15, ty = t >> 4;
  float acc[4][4] = {};
  for (int kk0 = 0; kk0 < 64; kk0 += 32) {
    for (int idx = t; idx < 64 * 32; idx += 256) {
      int ii = idx >> 5, kk = idx & 31;
      As[kk][ii] = G[(i0 + ii) * F + k0 + kk0 + kk];
      Bs[kk][ii] = G[(j0 + ii) * F + k0 + kk0 + kk];
    }
    __syncthreads();
#pragma unroll
    for (int k = 0; k < 32; ++k) {
      float a[4], b[4];
#pragma unroll
      for (int m = 0; m < 4; ++m) { a[m] = As[k][ty*4 + m]; b[m] = Bs[k][tx*4 + m]; }
#pragma unroll
      for (int r = 0; r < 4; ++r)
#pragma unroll
        for (int c = 0; c < 4; ++c) acc[r][c] += a[r] * b[c];
    }
    __syncthreads();
  }
  if (!fuse) {
#pragma unroll
    for (int r = 0; r < 4; ++r)
#pragma unroll
      for (int c = 0; c < 4; ++c)
        G[(i0 + ty*4 + r) * F + j0 + tx*4 + c] -= acc[r][c];
  } else {
#pragma unroll
    for (int r = 0; r < 4; ++r)
#pragma unroll
      for (int c = 0; c < 4; ++c)
        Ts[(ty*4 + r)*66 + tx*4 + c] =
            G[(i0 + ty*4 + r) * F + j0 + tx*4 + c] - acc[r][c];
    diag_factor(Ts);
    for (int idx = t; idx < 64 * 64; idx += 256) {
      int i = idx >> 6, j = idx & 63;
      if (j <= i) G[(i0 + i) * F + j0 + j] = Ts[i*66 + j];
    }
  }
}

// ---------------- invert diagonal 64x64 triangular block -> LI ----------------
__device__ void base_inv_phase(const float* __restrict__ G, float* __restrict__ LI,
                               int blk, float* Ts, float* invd) {
  int base = blk * 64, t = threadIdx.x;
  for (int idx = t; idx < 64 * 64; idx += 256) {
    int i = idx >> 6, j = idx & 63;
    Ts[i*66 + j] = G[(base + i) * F + base + j];
  }
  __syncthreads();
  if (t < 64) invd[t] = 1.0f / Ts[t*66 + t];
  __syncthreads();
  int l = t & 63, w = t >> 6;
  float v[16];
#pragma unroll
  for (int c = 0; c < 16; ++c) v[c] = (l == (w * 16 + c)) ? 1.0f : 0.0f;
#pragma unroll
  for (int j = 0; j < 64; ++j) {
    float dj = invd[j];
    float lj = (l > j) ? Ts[l*66 + j] : 0.0f;
#pragma unroll
    for (int c = 0; c < 16; ++c) {
      float x = __shfl(v[c], j, 64) * dj;
      v[c] = fmaf(-x, lj, v[c]);
    }
  }
  float dl = invd[l];
#pragma unroll
  for (int c = 0; c < 16; ++c)
    LI[(base + l) * F + base + w * 16 + c] = v[c] * dl;
}

// ================= k_mid: Cholesky + base-inv + zero-barrier solves =================
__global__ __launch_bounds__(256) void k_mid(float* __restrict__ G, float* __restrict__ LI,
                                             const float* __restrict__ Yb,
                                             float* __restrict__ Tb, float* __restrict__ meanT,
                                             int* __restrict__ cnt) {
  __shared__ float As[32][68];
  __shared__ float Bs[32][68];
  __shared__ float Ts[64 * 66];
  __shared__ float invd[64];
  __shared__ float Xs[32][20];
  int bar = 0;
  int b = blockIdx.x, t = threadIdx.x;

  // ---- diag k=0 ----
  if (b == 0) {
    for (int idx = t; idx < 64 * 64; idx += 256) {
      int i = idx >> 6, j = idx & 63;
      Ts[i*66 + j] = G[i * F + j];
    }
    diag_factor(Ts);
    for (int idx = t; idx < 64 * 64; idx += 256) {
      int i = idx >> 6, j = idx & 63;
      if (j <= i) G[i * F + j] = Ts[i*66 + j];
    }
  }
  gbar(cnt, ++bar);

  // ---- blocked right-looking Cholesky, diag(k+1) fused into upd(k) ----
  for (int k = 0; k < 8; ++k) {
    int k0 = k * 64;
    int n = 512 - k0;
    if (b < n / 16) panel_phase(G, k0, b, Ts, invd);
    gbar(cnt, ++bar);
    int nt = n / 64, ntiles = nt * (nt + 1) / 2;
    if (b < ntiles) {
      int ti = 0, bb = b;
      while (bb >= ti + 1) { bb -= ti + 1; ++ti; }
      int tj = bb;
      upd_phase(G, k0, ti, tj, (ti == 0 && tj == 0), As, Bs, Ts);
    }
    gbar(cnt, ++bar);
  }

  // ---- base inversions + zero upper-triangle LI tiles ----
  if (b < 9) {
    base_inv_phase(G, LI, b, Ts, invd);
  } else {
    int m0 = b - 9;
    for (int mm = m0; mm < 36; mm += 27) {
      int r = 0, rem = mm;
      while (rem >= 8 - r) { rem -= 8 - r; ++r; }
      int c = r + 1 + rem;
      for (int idx = t; idx < 64 * 16; idx += 256) {
        int i = idx >> 4, jj = idx & 15;
        ((float4*)&LI[(r * 64 + i) * F + c * 64])[jj] = make_float4(0.f, 0.f, 0.f, 0.f);
      }
    }
  }
  gbar(cnt, ++bar);

  // ---- zero-barrier substitution solves: LI cols (32 tasks) + T (16 tasks) ----
  if (b < 32) solve_LI(G, LI, b >> 2, b & 3, As, Xs);
  if (b >= 20) solve_T(G, LI, Yb, Tb, b - 20, As, Xs);
  gbar(cnt, ++bar);

  // ---- mean solve (backward substitution), 16 tasks ----
  if (b < 16) solve_M(G, LI, Tb, meanT, b, As, Xs);
}

// ================= k_gy: G and Y builds merged (z-split) =================
__global__ __launch_bounds__(256) void k_gy(const float* __restrict__ X,
                                            const float* __restrict__ u,
                                            const float* __restrict__ lp,
                                            float* __restrict__ G,
                                            float* __restrict__ Y) {
  __shared__ float As[32][68];
  __shared__ float Bs[32][68];
  int t = threadIdx.x, tx = t & 15, ty = t >> 4;
  if (blockIdx.z == 0) {
    int bi = blockIdx.y, bj = blockIdx.x;
    if (bj > bi) return;
    int f0 = bi * 64, g0 = bj * 64;
    float acc[4][4] = {};
    for (int i0 = 0; i0 < F; i0 += 32) {
      int col = t & 63, kr = t >> 6;
#pragma unroll
      for (int kk = 0; kk < 32; kk += 4) {
        int i = i0 + kr + kk;
        float e = expf(lp[i]);
        As[kr + kk][col] = e * X[i * F + f0 + col];
        Bs[kr + kk][col] = X[i * F + g0 + col];
      }
      __syncthreads();
      mm16(As, Bs, acc, tx, ty);
      __syncthreads();
    }
#pragma unroll
    for (int r = 0; r < 4; ++r) {
      int gr = f0 + ty*4 + r;
#pragma unroll
      for (int c = 0; c < 4; ++c) {
        int gc = g0 + tx*4 + c;
        float v = acc[r][c];
        if (gr == gc) v += PP;
        G[gr * F + gc] = v;
      }
    }
  } else {
    if (blockIdx.x >= 4) return;
    int bo = blockIdx.x, bf = blockIdx.y;
    int f0 = bf * 64, o0 = bo * 64;
    float acc[4][4] = {};
    for (int i0 = 0; i0 < F; i0 += 32) {
      {
        int col = t & 63, kr = t >> 6;
#pragma unroll
        for (int kk = 0; kk < 32; kk += 4) {
          int i = i0 + kr + kk;
          As[kr + kk][col] = expf(lp[i]) * X[i * F + f0 + col];
        }
        int oo = t >> 2, kq = t & 3;
        const float* ur = &u[(o0 + oo) * F + i0 + kq * 8];
        float4 u0 = *(const float4*)ur;
        float4 u1 = *(const float4*)(ur + 4);
        Bs[kq*8+0][oo] = u0.x; Bs[kq*8+1][oo] = u0.y;
        Bs[kq*8+2][oo] = u0.z; Bs[kq*8+3][oo] = u0.w;
        Bs[kq*8+4][oo] = u1.x; Bs[kq*8+5][oo] = u1.y;
        Bs[kq*8+6][oo] = u1.z; Bs[kq*8+7][oo] = u1.w;
      }
      __syncthreads();
      mm16(As, Bs, acc, tx, ty);
      __syncthreads();
    }
#pragma unroll
    for (int r = 0; r < 4; ++r) {
      float4 st = make_float4(acc[r][0], acc[r][1], acc[r][2], acc[r][3]);
      *(float4*)&Y[(f0 + ty*4 + r) * OUTC + o0 + tx*4] = st;
    }
  }
}

// ================= k_big: out = Z@Linv + mean, fused f64 logpq partials =================
__global__ __launch_bounds__(256) void k_big(const float* __restrict__ Z,
                                             const float* __restrict__ LI,
                                             const float* __restrict__ meanT,
                                             float* __restrict__ out,
                                             double* __restrict__ parts) {
  int bf = blockIdx.x, br = blockIdx.y;
  __shared__ float As[32][68];
  __shared__ float Bs[32][68];
  __shared__ double redA[256];
  __shared__ double redB[256];
  int t = threadIdx.x, tx = t & 15, ty = t >> 4;
  int f0 = bf * 64, r0 = br * 64;
  float acc[4][4] = {};
  double zsq = 0.0;
  for (int g0 = f0; g0 < F; g0 += 32) {
    {
      int rr = t >> 2, kq = t & 3;
      const float* zr = &Z[(r0 + rr) * F + g0 + kq * 8];
      float4 a0 = *(const float4*)zr;
      float4 a1 = *(const float4*)(zr + 4);
      if (bf == 0) {
        zsq += (double)a0.x*a0.x + (double)a0.y*a0.y + (double)a0.z*a0.z + (double)a0.w*a0.w
             + (double)a1.x*a1.x + (double)a1.y*a1.y + (double)a1.z*a1.z + (double)a1.w*a1.w;
      }
      As[kq*8+0][rr] = a0.x; As[kq*8+1][rr] = a0.y;
      As[kq*8+2][rr] = a0.z; As[kq*8+3][rr] = a0.w;
      As[kq*8+4][rr] = a1.x; As[kq*8+5][rr] = a1.y;
      As[kq*8+6][rr] = a1.z; As[kq*8+7][rr] = a1.w;
      int col = t & 63, kr = t >> 6;
#pragma unroll
      for (int kk = 0; kk < 32; kk += 4)
        Bs[kr + kk][col] = LI[(g0 + kr + kk) * F + f0 + col];
    }
    __syncthreads();
    mm16(As, Bs, acc, tx, ty);
    __syncthreads();
  }
  double ssq = 0.0;
#pragma unroll
  for (int r = 0; r < 4; ++r) {
    int row = r0 + ty*4 + r;
    int o = row & 255;
    float4 mv = *(const float4*)&meanT[o * F + f0 + tx*4];
    float4 st = make_float4(acc[r][0] + mv.x, acc[r][1] + mv.y,
                            acc[r][2] + mv.z, acc[r][3] + mv.w);
    *(float4*)&out[row * F + f0 + tx*4] = st;
    ssq += (double)st.x*st.x + (double)st.y*st.y + (double)st.z*st.z + (double)st.w*st.w;
  }
  redA[t] = ssq; redB[t] = zsq;
  __syncthreads();
  for (int o = 128; o > 0; o >>= 1) {
    if (t < o) { redA[t] += redA[t + o]; redB[t] += redB[t + o]; }
    __syncthreads();
  }
  if (t == 0) {
    int s = br >> 2;
    atomicAdd(&parts[s * 2 + 0], redA[0]);
    if (bf == 0) atomicAdd(&parts[s * 2 + 1], redB[0]);
  }
}

// ================= logpq final =================
__global__ __launch_bounds__(576) void k_logpq_final(const float* __restrict__ LI,
                                                     const double* __restrict__ parts,
                                                     float* __restrict__ out) {
  __shared__ double red[576];
  int t = threadIdx.x;
  red[t] = log((double)LI[t * F + t]);   // = -log(L[t][t])
  __syncthreads();
  for (int o = 512; o > 0; o >>= 1) {
    if (t < o && t + o < 576) red[t] += red[t + o];
    __syncthreads();
  }
  double ldsumLI = red[0];
  if (t < SNUM) {
    double ssq = parts[t * 2 + 0];
    double zsq = parts[t * 2 + 1];
    double pp = 576.0;
    double lpq = -0.5 * pp * ssq
               + 0.5 * (double)(OUTC * F) * log(pp)
               + 0.5 * zsq
               + (double)OUTC * ldsumLI;
    out[SNUM * OUTC * F + t] = (float)lpq;
  }
}

// ================= launch =================
extern "C" void kernel_launch(void* const* d_in, const int* in_sizes, int n_in,
                              void* d_out, int out_size, void* d_ws, size_t ws_size,
                              hipStream_t stream) {
  (void)in_sizes; (void)n_in; (void)out_size; (void)ws_size;
  const float* X  = (const float*)d_in[1];   // Xi_param [1,576,576]
  const float* u  = (const float*)d_in[2];   // u [256,576,1]
  const float* lp = (const float*)d_in[3];   // log_prec_scaled [1,1,576]
  const float* Z  = (const float*)d_in[4];   // Z [64,256,576,1]
  float* out = (float*)d_out;

  float* ws    = (float*)d_ws;
  float* G     = ws;                   // 331776
  float* LI    = ws + 331776;          // 331776
  float* Yb    = ws + 663552;          // 147456
  float* Tb    = ws + 811008;          // 147456 (T = L^{-1} Yb)
  float* meanT = ws + 958464;          // 147456
  double* parts = (double*)(ws + 1105920);        // 128 doubles (1024 B)
  int*    cnt   = (int*)(ws + 1105920 + 256);     // barrier counter

  hipMemsetAsync((void*)(ws + 1105920), 0, 1032, stream);
  k_gy<<<dim3(9, 9, 2), 256, 0, stream>>>(X, u, lp, G, Yb);
  k_mid<<<NBLK, 256, 0, stream>>>(G, LI, Yb, Tb, meanT, cnt);
  k_big<<<dim3(9, 256), 256, 0, stream>>>(Z, LI, meanT, out, parts);
  k_logpq_final<<<1, 576, 0, stream>>>(LI, parts, out);
}

// Round 10
// 774.103 us; speedup vs baseline: 1.2171x; 1.0308x over previous
//
#include <hip/hip_runtime.h>

#define F 576
#define OUTC 256
#define SNUM 64
#define PP 576.0f
#define NBLK 36

// ---------------- device barrier (round-7 best: single counter, hoisted fences) ----------------
__device__ __forceinline__ void gbar(int* cnt, int barid) {
  __syncthreads();
  if (threadIdx.x == 0) {
    __builtin_amdgcn_fence(__ATOMIC_RELEASE, "agent");
    __hip_atomic_fetch_add(cnt, 1, __ATOMIC_RELAXED, __HIP_MEMORY_SCOPE_AGENT);
    int target = barid * NBLK;
    while (__hip_atomic_load(cnt, __ATOMIC_RELAXED, __HIP_MEMORY_SCOPE_AGENT) < target) {
      __builtin_amdgcn_s_sleep(2);
    }
    __builtin_amdgcn_fence(__ATOMIC_ACQUIRE, "agent");
  }
  __syncthreads();
}

// ---------------- shared inner product (proven core) ----------------
__device__ __forceinline__ void mm16(const float (*As)[68], const float (*Bs)[68],
                                     float acc[4][4], int tx, int ty) {
#pragma unroll
  for (int k = 0; k < 32; ++k) {
    float4 a4 = *(const float4*)&As[k][ty * 4];
    float4 b4 = *(const float4*)&Bs[k][tx * 4];
    float av[4] = {a4.x, a4.y, a4.z, a4.w};
    float bv[4] = {b4.x, b4.y, b4.z, b4.w};
#pragma unroll
    for (int r = 0; r < 4; ++r)
#pragma unroll
      for (int c = 0; c < 4; ++c) acc[r][c] += av[r] * bv[c];
  }
}

// ---------------- generic 64x64 tile of C = sgn * A@B (A row-major) ----------------
__device__ void tile_gemm(const float* __restrict__ A, int lda,
                          const float* __restrict__ B, int ldb,
                          float* __restrict__ C, int ldc,
                          int m0, int n0, int K, float sgn,
                          float (*As)[68], float (*Bs)[68]) {
  int t = threadIdx.x, tx = t & 15, ty = t >> 4;
  float acc[4][4] = {};
  for (int k0 = 0; k0 < K; k0 += 32) {
    int rr = t >> 2, kq = t & 3;
    const float* ap = &A[(m0 + rr) * lda + k0 + kq * 8];
    float4 a0 = *(const float4*)ap;
    float4 a1 = *(const float4*)(ap + 4);
    As[kq*8+0][rr] = a0.x; As[kq*8+1][rr] = a0.y;
    As[kq*8+2][rr] = a0.z; As[kq*8+3][rr] = a0.w;
    As[kq*8+4][rr] = a1.x; As[kq*8+5][rr] = a1.y;
    As[kq*8+6][rr] = a1.z; As[kq*8+7][rr] = a1.w;
    int col = t & 63, kr = t >> 6;
#pragma unroll
    for (int kk = 0; kk < 32; kk += 4)
      Bs[kr + kk][col] = B[(k0 + kr + kk) * ldb + n0 + col];
    __syncthreads();
    mm16(As, Bs, acc, tx, ty);
    __syncthreads();
  }
#pragma unroll
  for (int r = 0; r < 4; ++r)
#pragma unroll
    for (int c = 0; c < 4; ++c)
      C[(m0 + ty*4 + r) * ldc + n0 + tx*4 + c] = sgn * acc[r][c];
}

// ---------------- tile GEMM with A stored TRANSPOSED (upper-G panels): A[m][k] = Aup[k*F + m] ----------------
__device__ void tile_gemm_up(const float* __restrict__ Aup,
                             const float* __restrict__ B, int ldb,
                             float* __restrict__ C, int ldc,
                             int m0, int n0, int K, float sgn,
                             float (*As)[68], float (*Bs)[68]) {
  int t = threadIdx.x, tx = t & 15, ty = t >> 4;
  float acc[4][4] = {};
  for (int k0 = 0; k0 < K; k0 += 32) {
    int col = t & 63, kr = t >> 6;
#pragma unroll
    for (int kk = 0; kk < 32; kk += 4) {
      As[kr + kk][col] = Aup[(k0 + kr + kk) * F + m0 + col];
      Bs[kr + kk][col] = B[(k0 + kr + kk) * ldb + n0 + col];
    }
    __syncthreads();
    mm16(As, Bs, acc, tx, ty);
    __syncthreads();
  }
#pragma unroll
  for (int r = 0; r < 4; ++r)
#pragma unroll
    for (int c = 0; c < 4; ++c)
      C[(m0 + ty*4 + r) * ldc + n0 + tx*4 + c] = sgn * acc[r][c];
}

// ---------------- serial 64x64 Cholesky on LDS tile (wave 0) ----------------
__device__ void diag_factor(float* Ts /* 64x66 */) {
  int t = threadIdx.x;
  __syncthreads();
  if (t < 64) {
    int l = t;
    float r[64];
#pragma unroll
    for (int g = 0; g < 64; ++g) r[g] = Ts[l*66 + g];
#pragma unroll
    for (int j = 0; j < 64; ++j) {
      float d = __shfl(r[j], j, 64);
      float inv = 1.0f / sqrtf(d);
      float c = r[j] * inv;
      r[j] = c;
#pragma unroll
      for (int g = j + 1; g < 64; ++g)
        r[g] = fmaf(-__shfl(c, g, 64), c, r[g]);
    }
#pragma unroll
    for (int g = 0; g < 64; ++g) Ts[l*66 + g] = r[g];
  }
  __syncthreads();
}

// ---------------- TRSM 64 rows vs diag(k): P(rowbase..+63) -> PT (k-major [col][row]) ----------------
__device__ void trsm64(const float* __restrict__ G, int rowbase, int k0,
                       const float* Ts, const float* invd, float* PT) {
  int t = threadIdx.x, l = t & 63, w = t >> 6;
  for (int pass = 0; pass < 4; ++pass) {
    int lr = pass * 16 + w * 4;
    int r0 = rowbase + lr;
    float v0 = G[(r0 + 0) * F + k0 + l];
    float v1 = G[(r0 + 1) * F + k0 + l];
    float v2 = G[(r0 + 2) * F + k0 + l];
    float v3 = G[(r0 + 3) * F + k0 + l];
#pragma unroll
    for (int j = 0; j < 64; ++j) {
      float dj = invd[j];
      float x0 = __shfl(v0, j, 64) * dj;
      float x1 = __shfl(v1, j, 64) * dj;
      float x2 = __shfl(v2, j, 64) * dj;
      float x3 = __shfl(v3, j, 64) * dj;
      if (l > j) {
        float lj = Ts[l*66 + j];
        v0 = fmaf(-x0, lj, v0);
        v1 = fmaf(-x1, lj, v1);
        v2 = fmaf(-x2, lj, v2);
        v3 = fmaf(-x3, lj, v3);
      }
    }
    float dl = invd[l];
    PT[l*68 + lr + 0] = v0 * dl;
    PT[l*68 + lr + 1] = v1 * dl;
    PT[l*68 + lr + 2] = v2 * dl;
    PT[l*68 + lr + 3] = v3 * dl;
  }
}

// ---------------- fused chol phase k: per-tile TRSM + rank-64 update (+diag(k+1) at (0,0)) ----------------
// Panels are stored TRANSPOSED into G's upper triangle: L[r][c] = G[c*F + r].
__device__ void chol_phase(float* __restrict__ G, int k, int ti, int tj,
                           float* Ts, float* invd, float* PaT, float* PbT) {
  int k0 = k * 64;
  int bi = k0 + 64 + ti * 64;
  int bj = k0 + 64 + tj * 64;
  int t = threadIdx.x, tx = t & 15, ty = t >> 4;
  for (int idx = t; idx < 64 * 64; idx += 256) {
    int i = idx >> 6, j = idx & 63;
    Ts[i*66 + j] = G[(k0 + i) * F + k0 + j];
  }
  __syncthreads();
  if (t < 64) invd[t] = 1.0f / Ts[t*66 + t];
  __syncthreads();
  trsm64(G, bi, k0, Ts, invd, PaT);
  if (tj < ti) trsm64(G, bj, k0, Ts, invd, PbT);
  __syncthreads();
  const float* PjT = (tj < ti) ? PbT : PaT;
  float acc[4][4] = {};
#pragma unroll 4
  for (int kk = 0; kk < 64; ++kk) {
    float4 a4 = *(const float4*)&PaT[kk*68 + ty * 4];
    float4 b4 = *(const float4*)&PjT[kk*68 + tx * 4];
    float av[4] = {a4.x, a4.y, a4.z, a4.w};
    float bv[4] = {b4.x, b4.y, b4.z, b4.w};
#pragma unroll
    for (int r = 0; r < 4; ++r)
#pragma unroll
      for (int c = 0; c < 4; ++c) acc[r][c] += av[r] * bv[c];
  }
  if (tj == 0) {   // write final L panel rows bi..bi+63 (transposed, upper triangle)
    for (int idx = t; idx < 64 * 64; idx += 256) {
      int c = idx >> 6, r = idx & 63;
      G[(k0 + c) * F + bi + r] = PaT[c*68 + r];
    }
  }
  if (ti == 0 && tj == 0) {
    __syncthreads();
#pragma unroll
    for (int r = 0; r < 4; ++r)
#pragma unroll
      for (int c = 0; c < 4; ++c)
        Ts[(ty*4 + r)*66 + tx*4 + c] =
            G[(bi + ty*4 + r) * F + bj + tx*4 + c] - acc[r][c];
    diag_factor(Ts);
    for (int idx = t; idx < 64 * 64; idx += 256) {
      int i = idx >> 6, j = idx & 63;
      if (j <= i) G[(bi + i) * F + bj + j] = Ts[i*66 + j];
    }
  } else {
#pragma unroll
    for (int r = 0; r < 4; ++r)
#pragma unroll
      for (int c = 0; c < 4; ++c)
        G[(bi + ty*4 + r) * F + bj + tx*4 + c] -= acc[r][c];
  }
}

// ---------------- invert diagonal 64x64 triangular block -> LI ----------------
__device__ void base_inv_phase(const float* __restrict__ G, float* __restrict__ LI,
                               int blk, float* Ts, float* invd) {
  int base = blk * 64, t = threadIdx.x;
  for (int idx = t; idx < 64 * 64; idx += 256) {
    int i = idx >> 6, j = idx & 63;
    Ts[i*66 + j] = G[(base + i) * F + base + j];
  }
  __syncthreads();
  if (t < 64) invd[t] = 1.0f / Ts[t*66 + t];
  __syncthreads();
  int l = t & 63, w = t >> 6;
  float v[16];
#pragma unroll
  for (int c = 0; c < 16; ++c) v[c] = (l == (w * 16 + c)) ? 1.0f : 0.0f;
#pragma unroll
  for (int j = 0; j < 64; ++j) {
    float dj = invd[j];
    float lj = (l > j) ? Ts[l*66 + j] : 0.0f;
#pragma unroll
    for (int c = 0; c < 16; ++c) {
      float x = __shfl(v[c], j, 64) * dj;
      v[c] = fmaf(-x, lj, v[c]);
    }
  }
  float dl = invd[l];
#pragma unroll
  for (int c = 0; c < 16; ++c)
    LI[(base + l) * F + base + w * 16 + c] = v[c] * dl;
}

// ---------------- meanT[o][f] = sum_g LI[g][f] T[g][o] ----------------
__device__ void mean_phase(const float* __restrict__ LI, const float* __restrict__ T,
                           float* __restrict__ meanT, int bf, int bo,
                           float (*As)[68], float (*Bs)[68]) {
  int t = threadIdx.x, tx = t & 15, ty = t >> 4;
  int f0 = bf * 64, o0 = bo * 64;
  float acc[4][4] = {};
  for (int g0 = f0; g0 < F; g0 += 32) {
    int col = t & 63, kr = t >> 6;
#pragma unroll
    for (int kk = 0; kk < 32; kk += 4) {
      As[kr + kk][col] = T[(g0 + kr + kk) * OUTC + o0 + col];
      Bs[kr + kk][col] = LI[(g0 + kr + kk) * F + f0 + col];
    }
    __syncthreads();
    mm16(As, Bs, acc, tx, ty);
    __syncthreads();
  }
#pragma unroll
  for (int r = 0; r < 4; ++r) {
    float4 st = make_float4(acc[r][0], acc[r][1], acc[r][2], acc[r][3]);
    *(float4*)&meanT[(o0 + ty*4 + r) * F + f0 + tx*4] = st;
  }
}

// ================= k_mid =================
__global__ __launch_bounds__(256) void k_mid(float* __restrict__ G, float* __restrict__ LI,
                                             const float* __restrict__ Yb,
                                             float* __restrict__ Tb, float* __restrict__ meanT,
                                             int* __restrict__ cnt) {
  __shared__ float As[32][68];
  __shared__ float Bs[32][68];
  __shared__ float Ts[64 * 66];
  __shared__ float invd[64];
  __shared__ float PaT[64 * 68];
  __shared__ float PbT[64 * 68];
  int bar = 0;
  int b = blockIdx.x, t = threadIdx.x;
  float* Tw = Tb;

  // ---- diag(0) ----
  if (b == 0) {
    for (int idx = t; idx < 64 * 64; idx += 256) {
      int i = idx >> 6, j = idx & 63;
      Ts[i*66 + j] = G[i * F + j];
    }
    diag_factor(Ts);
    for (int idx = t; idx < 64 * 64; idx += 256) {
      int i = idx >> 6, j = idx & 63;
      if (j <= i) G[i * F + j] = Ts[i*66 + j];
    }
  }
  gbar(cnt, ++bar);

  // ---- fused Cholesky: one phase per k ----
  for (int k = 0; k < 8; ++k) {
    int nt = 8 - k, ntiles = nt * (nt + 1) / 2;
    if (b < ntiles) {
      int ti = 0, bb = b;
      while (bb >= ti + 1) { bb -= ti + 1; ++ti; }
      chol_phase(G, k, ti, bb, Ts, invd, PaT, PbT);
    }
    gbar(cnt, ++bar);
  }

  // ---- base inversions + zero off-diagonal LI tiles (R7 verbatim) ----
  if (b < 9) {
    base_inv_phase(G, LI, b, Ts, invd);
  } else {
    int m = b - 9;
    for (int q = m; q < 72; q += 27) {
      int r = q / 8, cc = q % 8;
      int c = cc + (cc >= r ? 1 : 0);
      for (int idx = t; idx < 64 * 16; idx += 256) {
        int i = idx >> 4, jj = idx & 15;
        ((float4*)&LI[(r * 64 + i) * F + c * 64])[jj] = make_float4(0.f, 0.f, 0.f, 0.f);
      }
    }
  }
  gbar(cnt, ++bar);

  // ---- recursion (off-diag L read from upper-transposed G) ----
  // L1: 4 pairs n=64, merged producer/consumer
  if (b < 4) {
    tile_gemm_up(G + b*128*(F+1) + 64, LI + b*128*(F+1), F,
                 Tw + b*4096, 64, 0, 0, 64, 1.0f, As, Bs);
    tile_gemm(LI + 64*(F+1) + b*128*(F+1), F, Tw + b*4096, 64,
              LI + 64*F + b*128*(F+1), F, 0, 0, 64, -1.0f, As, Bs);
  }
  gbar(cnt, ++bar);
  // L2: 2 pairs n=128
  if (b < 8) {
    int z = b >> 2, tl = b & 3;
    tile_gemm_up(G + z*256*(F+1) + 128, LI + z*256*(F+1), F,
                 Tw + z*16384, 128, (tl>>1)*64, (tl&1)*64, 128, 1.0f, As, Bs);
  }
  gbar(cnt, ++bar);
  if (b < 8) {
    int z = b >> 2, tl = b & 3;
    tile_gemm(LI + 128*(F+1) + z*256*(F+1), F, Tw + z*16384, 128,
              LI + 128*F + z*256*(F+1), F, (tl>>1)*64, (tl&1)*64, 128, -1.0f, As, Bs);
  }
  gbar(cnt, ++bar);
  // L3: 1 pair n=256
  if (b < 16) tile_gemm_up(G + 256, LI, F, Tw, 256,
                           (b>>2)*64, (b&3)*64, 256, 1.0f, As, Bs);
  gbar(cnt, ++bar);
  if (b < 16) tile_gemm(LI + 256*(F+1), F, Tw, 256, LI + 256*F, F,
                        (b>>2)*64, (b&3)*64, 256, -1.0f, As, Bs);
  gbar(cnt, ++bar);
  // L4: 512+64, merged
  if (b < 8) {
    tile_gemm_up(G + 512, LI, F, Tw, 512, 0, b*64, 512, 1.0f, As, Bs);
    tile_gemm(LI + 512*(F+1), F, Tw, 512, LI + 512*F, F, 0, b*64, 64, -1.0f, As, Bs);
  }
  gbar(cnt, ++bar);

  // ---- gemm_T ----
  {
    int bg = b >> 2, bo = b & 3;
    tile_gemm(LI, F, Yb, OUTC, Tb, OUTC, bg * 64, bo * 64, bg * 64 + 64, 1.0f, As, Bs);
  }
  gbar(cnt, ++bar);

  // ---- gemm_mean ----
  {
    int bf = b >> 2, bo = b & 3;
    mean_phase(LI, Tb, meanT, bf, bo, As, Bs);
  }
}

// ================= k_gy: G and Y builds merged (z-split) =================
__global__ __launch_bounds__(256) void k_gy(const float* __restrict__ X,
                                            const float* __restrict__ u,
                                            const float* __restrict__ lp,
                                            float* __restrict__ G,
                                            float* __restrict__ Y) {
  __shared__ float As[32][68];
  __shared__ float Bs[32][68];
  int t = threadIdx.x, tx = t & 15, ty = t >> 4;
  if (blockIdx.z == 0) {
    int bi = blockIdx.y, bj = blockIdx.x;
    if (bj > bi) return;
    int f0 = bi * 64, g0 = bj * 64;
    float acc[4][4] = {};
    for (int i0 = 0; i0 < F; i0 += 32) {
      int col = t & 63, kr = t >> 6;
#pragma unroll
      for (int kk = 0; kk < 32; kk += 4) {
        int i = i0 + kr + kk;
        float e = expf(lp[i]);
        As[kr + kk][col] = e * X[i * F + f0 + col];
        Bs[kr + kk][col] = X[i * F + g0 + col];
      }
      __syncthreads();
      mm16(As, Bs, acc, tx, ty);
      __syncthreads();
    }
#pragma unroll
    for (int r = 0; r < 4; ++r) {
      int gr = f0 + ty*4 + r;
#pragma unroll
      for (int c = 0; c < 4; ++c) {
        int gc = g0 + tx*4 + c;
        float v = acc[r][c];
        if (gr == gc) v += PP;
        G[gr * F + gc] = v;
      }
    }
  } else {
    if (blockIdx.x >= 4) return;
    int bo = blockIdx.x, bf = blockIdx.y;
    int f0 = bf * 64, o0 = bo * 64;
    float acc[4][4] = {};
    for (int i0 = 0; i0 < F; i0 += 32) {
      {
        int col = t & 63, kr = t >> 6;
#pragma unroll
        for (int kk = 0; kk < 32; kk += 4) {
          int i = i0 + kr + kk;
          As[kr + kk][col] = expf(lp[i]) * X[i * F + f0 + col];
        }
        int oo = t >> 2, kq = t & 3;
        const float* ur = &u[(o0 + oo) * F + i0 + kq * 8];
        float4 u0 = *(const float4*)ur;
        float4 u1 = *(const float4*)(ur + 4);
        Bs[kq*8+0][oo] = u0.x; Bs[kq*8+1][oo] = u0.y;
        Bs[kq*8+2][oo] = u0.z; Bs[kq*8+3][oo] = u0.w;
        Bs[kq*8+4][oo] = u1.x; Bs[kq*8+5][oo] = u1.y;
        Bs[kq*8+6][oo] = u1.z; Bs[kq*8+7][oo] = u1.w;
      }
      __syncthreads();
      mm16(As, Bs, acc, tx, ty);
      __syncthreads();
    }
#pragma unroll
    for (int r = 0; r < 4; ++r) {
      float4 st = make_float4(acc[r][0], acc[r][1], acc[r][2], acc[r][3]);
      *(float4*)&Y[(f0 + ty*4 + r) * OUTC + o0 + tx*4] = st;
    }
  }
}

// ================= k_big: out = Z@Linv + mean, fused f64 logpq partials =================
__global__ __launch_bounds__(256) void k_big(const float* __restrict__ Z,
                                             const float* __restrict__ LI,
                                             const float* __restrict__ meanT,
                                             float* __restrict__ out,
                                             double* __restrict__ parts) {
  int bf = blockIdx.x, br = blockIdx.y;
  __shared__ float As[32][68];
  __shared__ float Bs[32][68];
  __shared__ double redA[256];
  __shared__ double redB[256];
  int t = threadIdx.x, tx = t & 15, ty = t >> 4;
  int f0 = bf * 64, r0 = br * 64;
  float acc[4][4] = {};
  double zsq = 0.0;
  for (int g0 = f0; g0 < F; g0 += 32) {
    {
      int rr = t >> 2, kq = t & 3;
      const float* zr = &Z[(r0 + rr) * F + g0 + kq * 8];
      float4 a0 = *(const float4*)zr;
      float4 a1 = *(const float4*)(zr + 4);
      if (bf == 0) {
        zsq += (double)a0.x*a0.x + (double)a0.y*a0.y + (double)a0.z*a0.z + (double)a0.w*a0.w
             + (double)a1.x*a1.x + (double)a1.y*a1.y + (double)a1.z*a1.z + (double)a1.w*a1.w;
      }
      As[kq*8+0][rr] = a0.x; As[kq*8+1][rr] = a0.y;
      As[kq*8+2][rr] = a0.z; As[kq*8+3][rr] = a0.w;
      As[kq*8+4][rr] = a1.x; As[kq*8+5][rr] = a1.y;
      As[kq*8+6][rr] = a1.z; As[kq*8+7][rr] = a1.w;
      int col = t & 63, kr = t >> 6;
#pragma unroll
      for (int kk = 0; kk < 32; kk += 4)
        Bs[kr + kk][col] = LI[(g0 + kr + kk) * F + f0 + col];
    }
    __syncthreads();
    mm16(As, Bs, acc, tx, ty);
    __syncthreads();
  }
  double ssq = 0.0;
#pragma unroll
  for (int r = 0; r < 4; ++r) {
    int row = r0 + ty*4 + r;
    int o = row & 255;
    float4 mv = *(const float4*)&meanT[o * F + f0 + tx*4];
    float4 st = make_float4(acc[r][0] + mv.x, acc[r][1] + mv.y,
                            acc[r][2] + mv.z, acc[r][3] + mv.w);
    *(float4*)&out[row * F + f0 + tx*4] = st;
    ssq += (double)st.x*st.x + (double)st.y*st.y + (double)st.z*st.z + (double)st.w*st.w;
  }
  redA[t] = ssq; redB[t] = zsq;
  __syncthreads();
  for (int o = 128; o > 0; o >>= 1) {
    if (t < o) { redA[t] += redA[t + o]; redB[t] += redB[t + o]; }
    __syncthreads();
  }
  if (t == 0) {
    int s = br >> 2;
    atomicAdd(&parts[s * 2 + 0], redA[0]);
    if (bf == 0) atomicAdd(&parts[s * 2 + 1], redB[0]);
  }
}

// ================= logpq final =================
__global__ __launch_bounds__(576) void k_logpq_final(const float* __restrict__ LI,
                                                     const double* __restrict__ parts,
                                                     float* __restrict__ out) {
  __shared__ double red[576];
  int t = threadIdx.x;
  red[t] = log((double)LI[t * F + t]);   // = -log(L[t][t])
  __syncthreads();
  for (int o = 512; o > 0; o >>= 1) {
    if (t < o && t + o < 576) red[t] += red[t + o];
    __syncthreads();
  }
  double ldsumLI = red[0];
  if (t < SNUM) {
    double ssq = parts[t * 2 + 0];
    double zsq = parts[t * 2 + 1];
    double pp = 576.0;
    double lpq = -0.5 * pp * ssq
               + 0.5 * (double)(OUTC * F) * log(pp)
               + 0.5 * zsq
               + (double)OUTC * ldsumLI;
    out[SNUM * OUTC * F + t] = (float)lpq;
  }
}

// ================= launch =================
extern "C" void kernel_launch(void* const* d_in, const int* in_sizes, int n_in,
                              void* d_out, int out_size, void* d_ws, size_t ws_size,
                              hipStream_t stream) {
  (void)in_sizes; (void)n_in; (void)out_size; (void)ws_size;
  const float* X  = (const float*)d_in[1];   // Xi_param [1,576,576]
  const float* u  = (const float*)d_in[2];   // u [256,576,1]
  const float* lp = (const float*)d_in[3];   // log_prec_scaled [1,1,576]
  const float* Z  = (const float*)d_in[4];   // Z [64,256,576,1]
  float* out = (float*)d_out;

  float* ws    = (float*)d_ws;
  float* G     = ws;                   // 331776 (L lower+diag; panels transposed in upper)
  float* LI    = ws + 331776;          // 331776
  float* Yb    = ws + 663552;          // 147456
  float* Tb    = ws + 811008;          // 147456 (also trigemm temp)
  float* meanT = ws + 958464;          // 147456
  double* parts = (double*)(ws + 1105920);        // 128 doubles (1024 B)
  int*    cnt   = (int*)(ws + 1105920 + 256);     // barrier counter

  hipMemsetAsync((void*)(ws + 1105920), 0, 1032, stream);
  k_gy<<<dim3(9, 9, 2), 256, 0, stream>>>(X, u, lp, G, Yb);
  k_mid<<<NBLK, 256, 0, stream>>>(G, LI, Yb, Tb, meanT, cnt);
  k_big<<<dim3(9, 256), 256, 0, stream>>>(Z, LI, meanT, out, parts);
  k_logpq_final<<<1, 576, 0, stream>>>(LI, parts, out);
}

// Round 11
// 651.290 us; speedup vs baseline: 1.4466x; 1.1886x over previous
//
#include <hip/hip_runtime.h>

#define F 576
#define OUTC 256
#define SNUM 64
#define PP 576.0f
#define NBLK 36

typedef unsigned short u16;
typedef __attribute__((ext_vector_type(8))) short short8;
typedef __attribute__((ext_vector_type(4))) float f32x4;

__device__ __forceinline__ u16 f2b_rne(float x) {
  unsigned u = __float_as_uint(x);
  unsigned r = (u + 0x7FFF + ((u >> 16) & 1)) >> 16;
  return (u16)r;
}

// ---------------- device barrier (R7 champion: single counter, hoisted fences) ----------------
__device__ __forceinline__ void gbar(int* cnt, int barid) {
  __syncthreads();
  if (threadIdx.x == 0) {
    __builtin_amdgcn_fence(__ATOMIC_RELEASE, "agent");
    __hip_atomic_fetch_add(cnt, 1, __ATOMIC_RELAXED, __HIP_MEMORY_SCOPE_AGENT);
    int target = barid * NBLK;
    while (__hip_atomic_load(cnt, __ATOMIC_RELAXED, __HIP_MEMORY_SCOPE_AGENT) < target) {
      __builtin_amdgcn_s_sleep(2);
    }
    __builtin_amdgcn_fence(__ATOMIC_ACQUIRE, "agent");
  }
  __syncthreads();
}

// ---------------- shared inner product (proven core) ----------------
__device__ __forceinline__ void mm16(const float (*As)[68], const float (*Bs)[68],
                                     float acc[4][4], int tx, int ty) {
#pragma unroll
  for (int k = 0; k < 32; ++k) {
    float4 a4 = *(const float4*)&As[k][ty * 4];
    float4 b4 = *(const float4*)&Bs[k][tx * 4];
    float av[4] = {a4.x, a4.y, a4.z, a4.w};
    float bv[4] = {b4.x, b4.y, b4.z, b4.w};
#pragma unroll
    for (int r = 0; r < 4; ++r)
#pragma unroll
      for (int c = 0; c < 4; ++c) acc[r][c] += av[r] * bv[c];
  }
}

// ---------------- generic 64x64 tile of C = sgn * A@B ----------------
__device__ void tile_gemm(const float* __restrict__ A, int lda,
                          const float* __restrict__ B, int ldb,
                          float* __restrict__ C, int ldc,
                          int m0, int n0, int K, float sgn,
                          float (*As)[68], float (*Bs)[68]) {
  int t = threadIdx.x, tx = t & 15, ty = t >> 4;
  float acc[4][4] = {};
  for (int k0 = 0; k0 < K; k0 += 32) {
    int rr = t >> 2, kq = t & 3;
    const float* ap = &A[(m0 + rr) * lda + k0 + kq * 8];
    float4 a0 = *(const float4*)ap;
    float4 a1 = *(const float4*)(ap + 4);
    As[kq*8+0][rr] = a0.x; As[kq*8+1][rr] = a0.y;
    As[kq*8+2][rr] = a0.z; As[kq*8+3][rr] = a0.w;
    As[kq*8+4][rr] = a1.x; As[kq*8+5][rr] = a1.y;
    As[kq*8+6][rr] = a1.z; As[kq*8+7][rr] = a1.w;
    int col = t & 63, kr = t >> 6;
#pragma unroll
    for (int kk = 0; kk < 32; kk += 4)
      Bs[kr + kk][col] = B[(k0 + kr + kk) * ldb + n0 + col];
    __syncthreads();
    mm16(As, Bs, acc, tx, ty);
    __syncthreads();
  }
#pragma unroll
  for (int r = 0; r < 4; ++r)
#pragma unroll
    for (int c = 0; c < 4; ++c)
      C[(m0 + ty*4 + r) * ldc + n0 + tx*4 + c] = sgn * acc[r][c];
}

// ---------------- serial 64x64 Cholesky on LDS tile (wave 0) ----------------
__device__ void diag_factor(float* Ts /* 64x66 */) {
  int t = threadIdx.x;
  __syncthreads();
  if (t < 64) {
    int l = t;
    float r[64];
#pragma unroll
    for (int g = 0; g < 64; ++g) r[g] = Ts[l*66 + g];
#pragma unroll
    for (int j = 0; j < 64; ++j) {
      float d = __shfl(r[j], j, 64);
      float inv = 1.0f / sqrtf(d);
      float c = r[j] * inv;
      r[j] = c;
#pragma unroll
      for (int g = j + 1; g < 64; ++g)
        r[g] = fmaf(-__shfl(c, g, 64), c, r[g]);
    }
#pragma unroll
    for (int g = 0; g < 64; ++g) Ts[l*66 + g] = r[g];
  }
  __syncthreads();
}

// ---------------- panel solve: 16 rows per block (4 waves x 4 rows) ----------------
__device__ void panel_phase(float* __restrict__ G, int k0, int b,
                            float* Ts, float* invd) {
  int t = threadIdx.x;
  for (int idx = t; idx < 64 * 64; idx += 256) {
    int i = idx >> 6, j = idx & 63;
    Ts[i*66 + j] = G[(k0 + i) * F + k0 + j];
  }
  __syncthreads();
  if (t < 64) invd[t] = 1.0f / Ts[t*66 + t];
  __syncthreads();
  int l = t & 63, w = t >> 6;
  int r0 = k0 + 64 + b * 16 + w * 4;
  float v0 = G[(r0 + 0) * F + k0 + l];
  float v1 = G[(r0 + 1) * F + k0 + l];
  float v2 = G[(r0 + 2) * F + k0 + l];
  float v3 = G[(r0 + 3) * F + k0 + l];
#pragma unroll
  for (int j = 0; j < 64; ++j) {
    float dj = invd[j];
    float x0 = __shfl(v0, j, 64) * dj;
    float x1 = __shfl(v1, j, 64) * dj;
    float x2 = __shfl(v2, j, 64) * dj;
    float x3 = __shfl(v3, j, 64) * dj;
    if (l > j) {
      float lj = Ts[l*66 + j];
      v0 = fmaf(-x0, lj, v0);
      v1 = fmaf(-x1, lj, v1);
      v2 = fmaf(-x2, lj, v2);
      v3 = fmaf(-x3, lj, v3);
    }
  }
  float dl = invd[l];
  G[(r0 + 0) * F + k0 + l] = v0 * dl;
  G[(r0 + 1) * F + k0 + l] = v1 * dl;
  G[(r0 + 2) * F + k0 + l] = v2 * dl;
  G[(r0 + 3) * F + k0 + l] = v3 * dl;
}

// ---------------- rank-64 trailing update tile (+ fused next-diag for tile (0,0)) ----------------
__device__ void upd_phase(float* __restrict__ G, int k0, int ti, int tj, bool fuse,
                          float (*As)[68], float (*Bs)[68], float* Ts) {
  int b0 = k0 + 64;
  int i0 = b0 + ti * 64, j0 = b0 + tj * 64;
  int t = threadIdx.x, tx = t & 15, ty = t >> 4;
  float acc[4][4] = {};
  for (int kk0 = 0; kk0 < 64; kk0 += 32) {
    for (int idx = t; idx < 64 * 32; idx += 256) {
      int ii = idx >> 5, kk = idx & 31;
      As[kk][ii] = G[(i0 + ii) * F + k0 + kk0 + kk];
      Bs[kk][ii] = G[(j0 + ii) * F + k0 + kk0 + kk];
    }
    __syncthreads();
#pragma unroll
    for (int k = 0; k < 32; ++k) {
      float a[4], b[4];
#pragma unroll
      for (int m = 0; m < 4; ++m) { a[m] = As[k][ty*4 + m]; b[m] = Bs[k][tx*4 + m]; }
#pragma unroll
      for (int r = 0; r < 4; ++r)
#pragma unroll
        for (int c = 0; c < 4; ++c) acc[r][c] += a[r] * b[c];
    }
    __syncthreads();
  }
  if (!fuse) {
#pragma unroll
    for (int r = 0; r < 4; ++r)
#pragma unroll
      for (int c = 0; c < 4; ++c)
        G[(i0 + ty*4 + r) * F + j0 + tx*4 + c] -= acc[r][c];
  } else {
#pragma unroll
    for (int r = 0; r < 4; ++r)
#pragma unroll
      for (int c = 0; c < 4; ++c)
        Ts[(ty*4 + r)*66 + tx*4 + c] =
            G[(i0 + ty*4 + r) * F + j0 + tx*4 + c] - acc[r][c];
    diag_factor(Ts);
    for (int idx = t; idx < 64 * 64; idx += 256) {
      int i = idx >> 6, j = idx & 63;
      if (j <= i) G[(i0 + i) * F + j0 + j] = Ts[i*66 + j];
    }
  }
}

// ---------------- invert diagonal 64x64 triangular block -> LI ----------------
__device__ void base_inv_phase(const float* __restrict__ G, float* __restrict__ LI,
                               int blk, float* Ts, float* invd) {
  int base = blk * 64, t = threadIdx.x;
  for (int idx = t; idx < 64 * 64; idx += 256) {
    int i = idx >> 6, j = idx & 63;
    Ts[i*66 + j] = G[(base + i) * F + base + j];
  }
  __syncthreads();
  if (t < 64) invd[t] = 1.0f / Ts[t*66 + t];
  __syncthreads();
  int l = t & 63, w = t >> 6;
  float v[16];
#pragma unroll
  for (int c = 0; c < 16; ++c) v[c] = (l == (w * 16 + c)) ? 1.0f : 0.0f;
#pragma unroll
  for (int j = 0; j < 64; ++j) {
    float dj = invd[j];
    float lj = (l > j) ? Ts[l*66 + j] : 0.0f;
#pragma unroll
    for (int c = 0; c < 16; ++c) {
      float x = __shfl(v[c], j, 64) * dj;
      v[c] = fmaf(-x, lj, v[c]);
    }
  }
  float dl = invd[l];
#pragma unroll
  for (int c = 0; c < 16; ++c)
    LI[(base + l) * F + base + w * 16 + c] = v[c] * dl;
}

// ---------------- meanT[o][f] = sum_g LI[g][f] T[g][o] ----------------
__device__ void mean_phase(const float* __restrict__ LI, const float* __restrict__ T,
                           float* __restrict__ meanT, int bf, int bo,
                           float (*As)[68], float (*Bs)[68]) {
  int t = threadIdx.x, tx = t & 15, ty = t >> 4;
  int f0 = bf * 64, o0 = bo * 64;
  float acc[4][4] = {};
  for (int g0 = f0; g0 < F; g0 += 32) {
    int col = t & 63, kr = t >> 6;
#pragma unroll
    for (int kk = 0; kk < 32; kk += 4) {
      As[kr + kk][col] = T[(g0 + kr + kk) * OUTC + o0 + col];
      Bs[kr + kk][col] = LI[(g0 + kr + kk) * F + f0 + col];
    }
    __syncthreads();
    mm16(As, Bs, acc, tx, ty);
    __syncthreads();
  }
#pragma unroll
  for (int r = 0; r < 4; ++r) {
    float4 st = make_float4(acc[r][0], acc[r][1], acc[r][2], acc[r][3]);
    *(float4*)&meanT[(o0 + ty*4 + r) * F + f0 + tx*4] = st;
  }
}

// ================= k_mid (R7 champion, verbatim) =================
__global__ __launch_bounds__(256) void k_mid(float* __restrict__ G, float* __restrict__ LI,
                                             const float* __restrict__ Yb,
                                             float* __restrict__ Tb, float* __restrict__ meanT,
                                             int* __restrict__ cnt) {
  __shared__ float As[32][68];
  __shared__ float Bs[32][68];
  __shared__ float Ts[64 * 66];
  __shared__ float invd[64];
  int bar = 0;
  int b = blockIdx.x, t = threadIdx.x;
  float* Tw = Tb;

  if (b == 0) {
    for (int idx = t; idx < 64 * 64; idx += 256) {
      int i = idx >> 6, j = idx & 63;
      Ts[i*66 + j] = G[i * F + j];
    }
    diag_factor(Ts);
    for (int idx = t; idx < 64 * 64; idx += 256) {
      int i = idx >> 6, j = idx & 63;
      if (j <= i) G[i * F + j] = Ts[i*66 + j];
    }
  }
  gbar(cnt, ++bar);

  for (int k = 0; k < 8; ++k) {
    int k0 = k * 64;
    int n = 512 - k0;
    if (b < n / 16) panel_phase(G, k0, b, Ts, invd);
    gbar(cnt, ++bar);
    int nt = n / 64, ntiles = nt * (nt + 1) / 2;
    if (b < ntiles) {
      int ti = 0, bb = b;
      while (bb >= ti + 1) { bb -= ti + 1; ++ti; }
      int tj = bb;
      upd_phase(G, k0, ti, tj, (ti == 0 && tj == 0), As, Bs, Ts);
    }
    gbar(cnt, ++bar);
  }

  if (b < 9) {
    base_inv_phase(G, LI, b, Ts, invd);
  } else {
    int m = b - 9;
    for (int q = m; q < 72; q += 27) {
      int r = q / 8, cc = q % 8;
      int c = cc + (cc >= r ? 1 : 0);
      for (int idx = t; idx < 64 * 16; idx += 256) {
        int i = idx >> 4, jj = idx & 15;
        ((float4*)&LI[(r * 64 + i) * F + c * 64])[jj] = make_float4(0.f, 0.f, 0.f, 0.f);
      }
    }
  }
  gbar(cnt, ++bar);

  // L1: 4 pairs n=64, merged
  if (b < 4) {
    tile_gemm(G + 64*F + b*128*(F+1), F, LI + b*128*(F+1), F,
              Tw + b*4096, 64, 0, 0, 64, 1.0f, As, Bs);
    tile_gemm(LI + 64*(F+1) + b*128*(F+1), F, Tw + b*4096, 64,
              LI + 64*F + b*128*(F+1), F, 0, 0, 64, -1.0f, As, Bs);
  }
  gbar(cnt, ++bar);
  // L2: 2 pairs n=128
  if (b < 8) {
    int z = b >> 2, tl = b & 3;
    tile_gemm(G + 128*F + z*256*(F+1), F, LI + z*256*(F+1), F,
              Tw + z*16384, 128, (tl>>1)*64, (tl&1)*64, 128, 1.0f, As, Bs);
  }
  gbar(cnt, ++bar);
  if (b < 8) {
    int z = b >> 2, tl = b & 3;
    tile_gemm(LI + 128*(F+1) + z*256*(F+1), F, Tw + z*16384, 128,
              LI + 128*F + z*256*(F+1), F, (tl>>1)*64, (tl&1)*64, 128, -1.0f, As, Bs);
  }
  gbar(cnt, ++bar);
  // L3: 1 pair n=256
  if (b < 16) tile_gemm(G + 256*F, F, LI, F, Tw, 256,
                        (b>>2)*64, (b&3)*64, 256, 1.0f, As, Bs);
  gbar(cnt, ++bar);
  if (b < 16) tile_gemm(LI + 256*(F+1), F, Tw, 256, LI + 256*F, F,
                        (b>>2)*64, (b&3)*64, 256, -1.0f, As, Bs);
  gbar(cnt, ++bar);
  // L4: 512+64, merged
  if (b < 8) {
    tile_gemm(G + 512*F, F, LI, F, Tw, 512, 0, b*64, 512, 1.0f, As, Bs);
    tile_gemm(LI + 512*(F+1), F, Tw, 512, LI + 512*F, F, 0, b*64, 64, -1.0f, As, Bs);
  }
  gbar(cnt, ++bar);

  {
    int bg = b >> 2, bo = b & 3;
    tile_gemm(LI, F, Yb, OUTC, Tb, OUTC, bg * 64, bo * 64, bg * 64 + 64, 1.0f, As, Bs);
  }
  gbar(cnt, ++bar);

  {
    int bf = b >> 2, bo = b & 3;
    mean_phase(LI, Tb, meanT, bf, bo, As, Bs);
  }
}

// ================= k_gy: G and Y builds merged (z-split) =================
__global__ __launch_bounds__(256) void k_gy(const float* __restrict__ X,
                                            const float* __restrict__ u,
                                            const float* __restrict__ lp,
                                            float* __restrict__ G,
                                            float* __restrict__ Y) {
  __shared__ float As[32][68];
  __shared__ float Bs[32][68];
  int t = threadIdx.x, tx = t & 15, ty = t >> 4;
  if (blockIdx.z == 0) {
    int bi = blockIdx.y, bj = blockIdx.x;
    if (bj > bi) return;
    int f0 = bi * 64, g0 = bj * 64;
    float acc[4][4] = {};
    for (int i0 = 0; i0 < F; i0 += 32) {
      int col = t & 63, kr = t >> 6;
#pragma unroll
      for (int kk = 0; kk < 32; kk += 4) {
        int i = i0 + kr + kk;
        float e = expf(lp[i]);
        As[kr + kk][col] = e * X[i * F + f0 + col];
        Bs[kr + kk][col] = X[i * F + g0 + col];
      }
      __syncthreads();
      mm16(As, Bs, acc, tx, ty);
      __syncthreads();
    }
#pragma unroll
    for (int r = 0; r < 4; ++r) {
      int gr = f0 + ty*4 + r;
#pragma unroll
      for (int c = 0; c < 4; ++c) {
        int gc = g0 + tx*4 + c;
        float v = acc[r][c];
        if (gr == gc) v += PP;
        G[gr * F + gc] = v;
      }
    }
  } else {
    if (blockIdx.x >= 4) return;
    int bo = blockIdx.x, bf = blockIdx.y;
    int f0 = bf * 64, o0 = bo * 64;
    float acc[4][4] = {};
    for (int i0 = 0; i0 < F; i0 += 32) {
      {
        int col = t & 63, kr = t >> 6;
#pragma unroll
        for (int kk = 0; kk < 32; kk += 4) {
          int i = i0 + kr + kk;
          As[kr + kk][col] = expf(lp[i]) * X[i * F + f0 + col];
        }
        int oo = t >> 2, kq = t & 3;
        const float* ur = &u[(o0 + oo) * F + i0 + kq * 8];
        float4 u0 = *(const float4*)ur;
        float4 u1 = *(const float4*)(ur + 4);
        Bs[kq*8+0][oo] = u0.x; Bs[kq*8+1][oo] = u0.y;
        Bs[kq*8+2][oo] = u0.z; Bs[kq*8+3][oo] = u0.w;
        Bs[kq*8+4][oo] = u1.x; Bs[kq*8+5][oo] = u1.y;
        Bs[kq*8+6][oo] = u1.z; Bs[kq*8+7][oo] = u1.w;
      }
      __syncthreads();
      mm16(As, Bs, acc, tx, ty);
      __syncthreads();
    }
#pragma unroll
    for (int r = 0; r < 4; ++r) {
      float4 st = make_float4(acc[r][0], acc[r][1], acc[r][2], acc[r][3]);
      *(float4*)&Y[(f0 + ty*4 + r) * OUTC + o0 + tx*4] = st;
    }
  }
}

// ================= k_split: LIT_H/L[f][g] = split-bf16 of Linv[g][f] =================
__global__ __launch_bounds__(256) void k_split(const float* __restrict__ LI,
                                               u16* __restrict__ H, u16* __restrict__ L) {
  __shared__ float Tt[64][65];
  int gb = blockIdx.x, fb = blockIdx.y;
  int t = threadIdx.x;
  for (int idx = t; idx < 4096; idx += 256) {
    int i = idx >> 6, j = idx & 63;
    Tt[i][j] = LI[(gb * 64 + i) * F + fb * 64 + j];
  }
  __syncthreads();
  for (int idx = t; idx < 4096; idx += 256) {
    int i = idx >> 6, j = idx & 63;
    float x = Tt[j][i];
    u16 h = f2b_rne(x);
    float hf = __uint_as_float((unsigned)h << 16);
    H[(fb * 64 + i) * F + gb * 64 + j] = h;
    L[(fb * 64 + i) * F + gb * 64 + j] = f2b_rne(x - hf);
  }
}

// ================= k_big: MFMA split-bf16 out = Z@Linv + mean, fused f64 partials =================
#define PADK 72
__global__ __launch_bounds__(256) void k_big(const float* __restrict__ Z,
                                             const u16* __restrict__ BHg,
                                             const u16* __restrict__ BLg,
                                             const float* __restrict__ meanT,
                                             float* __restrict__ out,
                                             double* __restrict__ parts) {
  int bf = blockIdx.x, br = blockIdx.y;
  __shared__ u16 ZH[64 * PADK];
  __shared__ u16 ZL[64 * PADK];
  __shared__ u16 BH[64 * PADK];
  __shared__ u16 BL[64 * PADK];
  __shared__ double redA[256];
  __shared__ double redB[256];
  int t = threadIdx.x, l = t & 63, w = t >> 6;
  int f0 = bf * 64, r0 = br * 64;
  int rr = t >> 2, kq = t & 3;
  f32x4 acc0 = {0.f,0.f,0.f,0.f}, acc1 = {0.f,0.f,0.f,0.f};
  f32x4 acc2 = {0.f,0.f,0.f,0.f}, acc3 = {0.f,0.f,0.f,0.f};
  double zsq = 0.0;

  for (int g0 = f0; g0 < F; g0 += 64) {
    // ---- stage Z (64 rows x 64 k), split hi/lo ----
    {
      const float* zp = &Z[(r0 + rr) * F + g0 + kq * 16];
      float xs[16];
      *(float4*)&xs[0]  = *(const float4*)(zp + 0);
      *(float4*)&xs[4]  = *(const float4*)(zp + 4);
      *(float4*)&xs[8]  = *(const float4*)(zp + 8);
      *(float4*)&xs[12] = *(const float4*)(zp + 12);
      u16 hh[16], ll[16];
#pragma unroll
      for (int j = 0; j < 16; ++j) {
        u16 h = f2b_rne(xs[j]);
        float hf = __uint_as_float((unsigned)h << 16);
        hh[j] = h;
        ll[j] = f2b_rne(xs[j] - hf);
        if (bf == 0) zsq += (double)xs[j] * xs[j];
      }
      *(short8*)&ZH[rr * PADK + kq * 16 + 0] = *(short8*)&hh[0];
      *(short8*)&ZH[rr * PADK + kq * 16 + 8] = *(short8*)&hh[8];
      *(short8*)&ZL[rr * PADK + kq * 16 + 0] = *(short8*)&ll[0];
      *(short8*)&ZL[rr * PADK + kq * 16 + 8] = *(short8*)&ll[8];
      // ---- stage B (pre-split bf16, transposed): BHg[f][g] ----
      const u16* bh = &BHg[(f0 + rr) * F + g0 + kq * 16];
      const u16* bl = &BLg[(f0 + rr) * F + g0 + kq * 16];
      *(short8*)&BH[rr * PADK + kq * 16 + 0] = *(const short8*)(bh + 0);
      *(short8*)&BH[rr * PADK + kq * 16 + 8] = *(const short8*)(bh + 8);
      *(short8*)&BL[rr * PADK + kq * 16 + 0] = *(const short8*)(bl + 0);
      *(short8*)&BL[rr * PADK + kq * 16 + 8] = *(const short8*)(bl + 8);
    }
    __syncthreads();
    // ---- MFMA: wave w owns rows w*16..w*16+15; 4 col-frags; 2 k-substeps ----
#pragma unroll
    for (int kk = 0; kk < 2; ++kk) {
      int aoff = (w * 16 + (l & 15)) * PADK + kk * 32 + (l >> 4) * 8;
      short8 ah = *(short8*)&ZH[aoff];
      short8 al = *(short8*)&ZL[aoff];
      int b0o = ((l & 15)) * PADK + kk * 32 + (l >> 4) * 8;
      {
        short8 bh = *(short8*)&BH[b0o];
        short8 bl = *(short8*)&BL[b0o];
        acc0 = __builtin_amdgcn_mfma_f32_16x16x32_bf16(ah, bh, acc0, 0, 0, 0);
        acc0 = __builtin_amdgcn_mfma_f32_16x16x32_bf16(ah, bl, acc0, 0, 0, 0);
        acc0 = __builtin_amdgcn_mfma_f32_16x16x32_bf16(al, bh, acc0, 0, 0, 0);
      }
      {
        short8 bh = *(short8*)&BH[b0o + 16 * PADK];
        short8 bl = *(short8*)&BL[b0o + 16 * PADK];
        acc1 = __builtin_amdgcn_mfma_f32_16x16x32_bf16(ah, bh, acc1, 0, 0, 0);
        acc1 = __builtin_amdgcn_mfma_f32_16x16x32_bf16(ah, bl, acc1, 0, 0, 0);
        acc1 = __builtin_amdgcn_mfma_f32_16x16x32_bf16(al, bh, acc1, 0, 0, 0);
      }
      {
        short8 bh = *(short8*)&BH[b0o + 32 * PADK];
        short8 bl = *(short8*)&BL[b0o + 32 * PADK];
        acc2 = __builtin_amdgcn_mfma_f32_16x16x32_bf16(ah, bh, acc2, 0, 0, 0);
        acc2 = __builtin_amdgcn_mfma_f32_16x16x32_bf16(ah, bl, acc2, 0, 0, 0);
        acc2 = __builtin_amdgcn_mfma_f32_16x16x32_bf16(al, bh, acc2, 0, 0, 0);
      }
      {
        short8 bh = *(short8*)&BH[b0o + 48 * PADK];
        short8 bl = *(short8*)&BL[b0o + 48 * PADK];
        acc3 = __builtin_amdgcn_mfma_f32_16x16x32_bf16(ah, bh, acc3, 0, 0, 0);
        acc3 = __builtin_amdgcn_mfma_f32_16x16x32_bf16(ah, bl, acc3, 0, 0, 0);
        acc3 = __builtin_amdgcn_mfma_f32_16x16x32_bf16(al, bh, acc3, 0, 0, 0);
      }
    }
    __syncthreads();
  }

  // ---- epilogue: add mean, store, f64 partials ----
  double ssq = 0.0;
  int colb = l & 15, rq = l >> 4;
#pragma unroll
  for (int c = 0; c < 4; ++c) {
    f32x4 a = (c == 0) ? acc0 : (c == 1) ? acc1 : (c == 2) ? acc2 : acc3;
#pragma unroll
    for (int r = 0; r < 4; ++r) {
      int row = r0 + w * 16 + rq * 4 + r;
      int col = f0 + c * 16 + colb;
      float v = a[r] + meanT[(row & 255) * F + col];
      out[row * F + col] = v;
      ssq += (double)v * v;
    }
  }
  redA[t] = ssq; redB[t] = zsq;
  __syncthreads();
  for (int o = 128; o > 0; o >>= 1) {
    if (t < o) { redA[t] += redA[t + o]; redB[t] += redB[t + o]; }
    __syncthreads();
  }
  if (t == 0) {
    int s = br >> 2;
    atomicAdd(&parts[s * 2 + 0], redA[0]);
    if (bf == 0) atomicAdd(&parts[s * 2 + 1], redB[0]);
  }
}

// ================= logpq final =================
__global__ __launch_bounds__(576) void k_logpq_final(const float* __restrict__ LI,
                                                     const double* __restrict__ parts,
                                                     float* __restrict__ out) {
  __shared__ double red[576];
  int t = threadIdx.x;
  red[t] = log((double)LI[t * F + t]);   // = -log(L[t][t])
  __syncthreads();
  for (int o = 512; o > 0; o >>= 1) {
    if (t < o && t + o < 576) red[t] += red[t + o];
    __syncthreads();
  }
  double ldsumLI = red[0];
  if (t < SNUM) {
    double ssq = parts[t * 2 + 0];
    double zsq = parts[t * 2 + 1];
    double pp = 576.0;
    double lpq = -0.5 * pp * ssq
               + 0.5 * (double)(OUTC * F) * log(pp)
               + 0.5 * zsq
               + (double)OUTC * ldsumLI;
    out[SNUM * OUTC * F + t] = (float)lpq;
  }
}

// ================= launch =================
extern "C" void kernel_launch(void* const* d_in, const int* in_sizes, int n_in,
                              void* d_out, int out_size, void* d_ws, size_t ws_size,
                              hipStream_t stream) {
  (void)in_sizes; (void)n_in; (void)out_size; (void)ws_size;
  const float* X  = (const float*)d_in[1];   // Xi_param [1,576,576]
  const float* u  = (const float*)d_in[2];   // u [256,576,1]
  const float* lp = (const float*)d_in[3];   // log_prec_scaled [1,1,576]
  const float* Z  = (const float*)d_in[4];   // Z [64,256,576,1]
  float* out = (float*)d_out;

  float* ws    = (float*)d_ws;
  float* G     = ws;                   // 331776 (L factor; reused as LIT after k_mid)
  float* LI    = ws + 331776;          // 331776
  float* Yb    = ws + 663552;          // 147456
  float* Tb    = ws + 811008;          // 147456 (also trigemm temp)
  float* meanT = ws + 958464;          // 147456
  double* parts = (double*)(ws + 1105920);        // 128 doubles
  int*    cnt   = (int*)(ws + 1105920 + 256);     // barrier counter
  u16* LIT_H = (u16*)G;                // 331776 u16 (overwrites G after k_mid)
  u16* LIT_L = LIT_H + 331776;         // 331776 u16

  hipMemsetAsync((void*)(ws + 1105920), 0, 1032, stream);
  k_gy<<<dim3(9, 9, 2), 256, 0, stream>>>(X, u, lp, G, Yb);
  k_mid<<<NBLK, 256, 0, stream>>>(G, LI, Yb, Tb, meanT, cnt);
  k_split<<<dim3(9, 9), 256, 0, stream>>>(LI, LIT_H, LIT_L);
  k_big<<<dim3(9, 256), 256, 0, stream>>>(Z, LIT_H, LIT_L, meanT, out, parts);
  k_logpq_final<<<1, 576, 0, stream>>>(LI, parts, out);
}

// Round 12
// 648.775 us; speedup vs baseline: 1.4522x; 1.0039x over previous
//
#include <hip/hip_runtime.h>

#define F 576
#define OUTC 256
#define SNUM 64
#define PP 576.0f
#define NBLK 36

typedef unsigned short u16;
typedef __attribute__((ext_vector_type(8))) short short8;
typedef __attribute__((ext_vector_type(4))) float f32x4;

__device__ __forceinline__ u16 f2b_rne(float x) {
  unsigned u = __float_as_uint(x);
  unsigned r = (u + 0x7FFF + ((u >> 16) & 1)) >> 16;
  return (u16)r;
}

// ---------------- device barrier v2: arrival counter + separate publish line ----------------
// Arrivals: release-fence + relaxed fetch_add on cnt. Only block 0 polls cnt; it then
// publishes gen (separate cache line) with a release-fence. Others poll gen (1 writer,
// N readers -> no RMW/poll interference on the arrival line). One wb/inv per block/barrier.
__device__ __forceinline__ void gbar(int* cnt, int* gen, int b, int barid) {
  __syncthreads();
  if (threadIdx.x == 0) {
    __builtin_amdgcn_fence(__ATOMIC_RELEASE, "agent");
    __hip_atomic_fetch_add(cnt, 1, __ATOMIC_RELAXED, __HIP_MEMORY_SCOPE_AGENT);
    if (b == 0) {
      int target = barid * NBLK;
      while (__hip_atomic_load(cnt, __ATOMIC_RELAXED, __HIP_MEMORY_SCOPE_AGENT) < target) {
        __builtin_amdgcn_s_sleep(1);
      }
      __builtin_amdgcn_fence(__ATOMIC_ACQUIRE, "agent");
      __builtin_amdgcn_fence(__ATOMIC_RELEASE, "agent");
      __hip_atomic_store(gen, barid, __ATOMIC_RELAXED, __HIP_MEMORY_SCOPE_AGENT);
    } else {
      while (__hip_atomic_load(gen, __ATOMIC_RELAXED, __HIP_MEMORY_SCOPE_AGENT) < barid) {
        __builtin_amdgcn_s_sleep(1);
      }
    }
    __builtin_amdgcn_fence(__ATOMIC_ACQUIRE, "agent");
  }
  __syncthreads();
}

// ---------------- shared inner product (proven core) ----------------
__device__ __forceinline__ void mm16(const float (*As)[68], const float (*Bs)[68],
                                     float acc[4][4], int tx, int ty) {
#pragma unroll
  for (int k = 0; k < 32; ++k) {
    float4 a4 = *(const float4*)&As[k][ty * 4];
    float4 b4 = *(const float4*)&Bs[k][tx * 4];
    float av[4] = {a4.x, a4.y, a4.z, a4.w};
    float bv[4] = {b4.x, b4.y, b4.z, b4.w};
#pragma unroll
    for (int r = 0; r < 4; ++r)
#pragma unroll
      for (int c = 0; c < 4; ++c) acc[r][c] += av[r] * bv[c];
  }
}

// ---------------- generic 64x64 tile of C = sgn * A@B ----------------
__device__ void tile_gemm(const float* __restrict__ A, int lda,
                          const float* __restrict__ B, int ldb,
                          float* __restrict__ C, int ldc,
                          int m0, int n0, int K, float sgn,
                          float (*As)[68], float (*Bs)[68]) {
  int t = threadIdx.x, tx = t & 15, ty = t >> 4;
  float acc[4][4] = {};
  for (int k0 = 0; k0 < K; k0 += 32) {
    int rr = t >> 2, kq = t & 3;
    const float* ap = &A[(m0 + rr) * lda + k0 + kq * 8];
    float4 a0 = *(const float4*)ap;
    float4 a1 = *(const float4*)(ap + 4);
    As[kq*8+0][rr] = a0.x; As[kq*8+1][rr] = a0.y;
    As[kq*8+2][rr] = a0.z; As[kq*8+3][rr] = a0.w;
    As[kq*8+4][rr] = a1.x; As[kq*8+5][rr] = a1.y;
    As[kq*8+6][rr] = a1.z; As[kq*8+7][rr] = a1.w;
    int col = t & 63, kr = t >> 6;
#pragma unroll
    for (int kk = 0; kk < 32; kk += 4)
      Bs[kr + kk][col] = B[(k0 + kr + kk) * ldb + n0 + col];
    __syncthreads();
    mm16(As, Bs, acc, tx, ty);
    __syncthreads();
  }
#pragma unroll
  for (int r = 0; r < 4; ++r)
#pragma unroll
    for (int c = 0; c < 4; ++c)
      C[(m0 + ty*4 + r) * ldc + n0 + tx*4 + c] = sgn * acc[r][c];
}

// ---------------- serial 64x64 Cholesky on LDS tile (wave 0) ----------------
__device__ void diag_factor(float* Ts /* 64x66 */) {
  int t = threadIdx.x;
  __syncthreads();
  if (t < 64) {
    int l = t;
    float r[64];
#pragma unroll
    for (int g = 0; g < 64; ++g) r[g] = Ts[l*66 + g];
#pragma unroll
    for (int j = 0; j < 64; ++j) {
      float d = __shfl(r[j], j, 64);
      float inv = 1.0f / sqrtf(d);
      float c = r[j] * inv;
      r[j] = c;
#pragma unroll
      for (int g = j + 1; g < 64; ++g)
        r[g] = fmaf(-__shfl(c, g, 64), c, r[g]);
    }
#pragma unroll
    for (int g = 0; g < 64; ++g) Ts[l*66 + g] = r[g];
  }
  __syncthreads();
}

// ---------------- panel solve: 16 rows per block (4 waves x 4 rows) ----------------
__device__ void panel_phase(float* __restrict__ G, int k0, int b,
                            float* Ts, float* invd) {
  int t = threadIdx.x;
  for (int idx = t; idx < 64 * 64; idx += 256) {
    int i = idx >> 6, j = idx & 63;
    Ts[i*66 + j] = G[(k0 + i) * F + k0 + j];
  }
  __syncthreads();
  if (t < 64) invd[t] = 1.0f / Ts[t*66 + t];
  __syncthreads();
  int l = t & 63, w = t >> 6;
  int r0 = k0 + 64 + b * 16 + w * 4;
  float v0 = G[(r0 + 0) * F + k0 + l];
  float v1 = G[(r0 + 1) * F + k0 + l];
  float v2 = G[(r0 + 2) * F + k0 + l];
  float v3 = G[(r0 + 3) * F + k0 + l];
#pragma unroll
  for (int j = 0; j < 64; ++j) {
    float dj = invd[j];
    float x0 = __shfl(v0, j, 64) * dj;
    float x1 = __shfl(v1, j, 64) * dj;
    float x2 = __shfl(v2, j, 64) * dj;
    float x3 = __shfl(v3, j, 64) * dj;
    if (l > j) {
      float lj = Ts[l*66 + j];
      v0 = fmaf(-x0, lj, v0);
      v1 = fmaf(-x1, lj, v1);
      v2 = fmaf(-x2, lj, v2);
      v3 = fmaf(-x3, lj, v3);
    }
  }
  float dl = invd[l];
  G[(r0 + 0) * F + k0 + l] = v0 * dl;
  G[(r0 + 1) * F + k0 + l] = v1 * dl;
  G[(r0 + 2) * F + k0 + l] = v2 * dl;
  G[(r0 + 3) * F + k0 + l] = v3 * dl;
}

// ---------------- rank-64 trailing update tile (+ fused next-diag for tile (0,0)) ----------------
__device__ void upd_phase(float* __restrict__ G, int k0, int ti, int tj, bool fuse,
                          float (*As)[68], float (*Bs)[68], float* Ts) {
  int b0 = k0 + 64;
  int i0 = b0 + ti * 64, j0 = b0 + tj * 64;
  int t = threadIdx.x, tx = t & 15, ty = t >> 4;
  float acc[4][4] = {};
  for (int kk0 = 0; kk0 < 64; kk0 += 32) {
    for (int idx = t; idx < 64 * 32; idx += 256) {
      int ii = idx >> 5, kk = idx & 31;
      As[kk][ii] = G[(i0 + ii) * F + k0 + kk0 + kk];
      Bs[kk][ii] = G[(j0 + ii) * F + k0 + kk0 + kk];
    }
    __syncthreads();
#pragma unroll
    for (int k = 0; k < 32; ++k) {
      float a[4], b[4];
#pragma unroll
      for (int m = 0; m < 4; ++m) { a[m] = As[k][ty*4 + m]; b[m] = Bs[k][tx*4 + m]; }
#pragma unroll
      for (int r = 0; r < 4; ++r)
#pragma unroll
        for (int c = 0; c < 4; ++c) acc[r][c] += a[r] * b[c];
    }
    __syncthreads();
  }
  if (!fuse) {
#pragma unroll
    for (int r = 0; r < 4; ++r)
#pragma unroll
      for (int c = 0; c < 4; ++c)
        G[(i0 + ty*4 + r) * F + j0 + tx*4 + c] -= acc[r][c];
  } else {
#pragma unroll
    for (int r = 0; r < 4; ++r)
#pragma unroll
      for (int c = 0; c < 4; ++c)
        Ts[(ty*4 + r)*66 + tx*4 + c] =
            G[(i0 + ty*4 + r) * F + j0 + tx*4 + c] - acc[r][c];
    diag_factor(Ts);
    for (int idx = t; idx < 64 * 64; idx += 256) {
      int i = idx >> 6, j = idx & 63;
      if (j <= i) G[(i0 + i) * F + j0 + j] = Ts[i*66 + j];
    }
  }
}

// ---------------- invert diagonal 64x64 triangular block -> LI ----------------
__device__ void base_inv_phase(const float* __restrict__ G, float* __restrict__ LI,
                               int blk, float* Ts, float* invd) {
  int base = blk * 64, t = threadIdx.x;
  for (int idx = t; idx < 64 * 64; idx += 256) {
    int i = idx >> 6, j = idx & 63;
    Ts[i*66 + j] = G[(base + i) * F + base + j];
  }
  __syncthreads();
  if (t < 64) invd[t] = 1.0f / Ts[t*66 + t];
  __syncthreads();
  int l = t & 63, w = t >> 6;
  float v[16];
#pragma unroll
  for (int c = 0; c < 16; ++c) v[c] = (l == (w * 16 + c)) ? 1.0f : 0.0f;
#pragma unroll
  for (int j = 0; j < 64; ++j) {
    float dj = invd[j];
    float lj = (l > j) ? Ts[l*66 + j] : 0.0f;
#pragma unroll
    for (int c = 0; c < 16; ++c) {
      float x = __shfl(v[c], j, 64) * dj;
      v[c] = fmaf(-x, lj, v[c]);
    }
  }
  float dl = invd[l];
#pragma unroll
  for (int c = 0; c < 16; ++c)
    LI[(base + l) * F + base + w * 16 + c] = v[c] * dl;
}

// ---------------- meanT[o][f] = sum_g LI[g][f] T[g][o] ----------------
__device__ void mean_phase(const float* __restrict__ LI, const float* __restrict__ T,
                           float* __restrict__ meanT, int bf, int bo,
                           float (*As)[68], float (*Bs)[68]) {
  int t = threadIdx.x, tx = t & 15, ty = t >> 4;
  int f0 = bf * 64, o0 = bo * 64;
  float acc[4][4] = {};
  for (int g0 = f0; g0 < F; g0 += 32) {
    int col = t & 63, kr = t >> 6;
#pragma unroll
    for (int kk = 0; kk < 32; kk += 4) {
      As[kr + kk][col] = T[(g0 + kr + kk) * OUTC + o0 + col];
      Bs[kr + kk][col] = LI[(g0 + kr + kk) * F + f0 + col];
    }
    __syncthreads();
    mm16(As, Bs, acc, tx, ty);
    __syncthreads();
  }
#pragma unroll
  for (int r = 0; r < 4; ++r) {
    float4 st = make_float4(acc[r][0], acc[r][1], acc[r][2], acc[r][3]);
    *(float4*)&meanT[(o0 + ty*4 + r) * F + f0 + tx*4] = st;
  }
}

// ================= k_mid (R11 structure, barrier v2) =================
__global__ __launch_bounds__(256) void k_mid(float* __restrict__ G, float* __restrict__ LI,
                                             const float* __restrict__ Yb,
                                             float* __restrict__ Tb, float* __restrict__ meanT,
                                             int* __restrict__ cnt, int* __restrict__ gen) {
  __shared__ float As[32][68];
  __shared__ float Bs[32][68];
  __shared__ float Ts[64 * 66];
  __shared__ float invd[64];
  int bar = 0;
  int b = blockIdx.x, t = threadIdx.x;
  float* Tw = Tb;

  if (b == 0) {
    for (int idx = t; idx < 64 * 64; idx += 256) {
      int i = idx >> 6, j = idx & 63;
      Ts[i*66 + j] = G[i * F + j];
    }
    diag_factor(Ts);
    for (int idx = t; idx < 64 * 64; idx += 256) {
      int i = idx >> 6, j = idx & 63;
      if (j <= i) G[i * F + j] = Ts[i*66 + j];
    }
  }
  gbar(cnt, gen, b, ++bar);

  for (int k = 0; k < 8; ++k) {
    int k0 = k * 64;
    int n = 512 - k0;
    if (b < n / 16) panel_phase(G, k0, b, Ts, invd);
    gbar(cnt, gen, b, ++bar);
    int nt = n / 64, ntiles = nt * (nt + 1) / 2;
    if (b < ntiles) {
      int ti = 0, bb = b;
      while (bb >= ti + 1) { bb -= ti + 1; ++ti; }
      int tj = bb;
      upd_phase(G, k0, ti, tj, (ti == 0 && tj == 0), As, Bs, Ts);
    }
    gbar(cnt, gen, b, ++bar);
  }

  if (b < 9) {
    base_inv_phase(G, LI, b, Ts, invd);
  } else {
    int m = b - 9;
    for (int q = m; q < 72; q += 27) {
      int r = q / 8, cc = q % 8;
      int c = cc + (cc >= r ? 1 : 0);
      for (int idx = t; idx < 64 * 16; idx += 256) {
        int i = idx >> 4, jj = idx & 15;
        ((float4*)&LI[(r * 64 + i) * F + c * 64])[jj] = make_float4(0.f, 0.f, 0.f, 0.f);
      }
    }
  }
  gbar(cnt, gen, b, ++bar);

  // L1: 4 pairs n=64, merged
  if (b < 4) {
    tile_gemm(G + 64*F + b*128*(F+1), F, LI + b*128*(F+1), F,
              Tw + b*4096, 64, 0, 0, 64, 1.0f, As, Bs);
    tile_gemm(LI + 64*(F+1) + b*128*(F+1), F, Tw + b*4096, 64,
              LI + 64*F + b*128*(F+1), F, 0, 0, 64, -1.0f, As, Bs);
  }
  gbar(cnt, gen, b, ++bar);
  // L2: 2 pairs n=128
  if (b < 8) {
    int z = b >> 2, tl = b & 3;
    tile_gemm(G + 128*F + z*256*(F+1), F, LI + z*256*(F+1), F,
              Tw + z*16384, 128, (tl>>1)*64, (tl&1)*64, 128, 1.0f, As, Bs);
  }
  gbar(cnt, gen, b, ++bar);
  if (b < 8) {
    int z = b >> 2, tl = b & 3;
    tile_gemm(LI + 128*(F+1) + z*256*(F+1), F, Tw + z*16384, 128,
              LI + 128*F + z*256*(F+1), F, (tl>>1)*64, (tl&1)*64, 128, -1.0f, As, Bs);
  }
  gbar(cnt, gen, b, ++bar);
  // L3: 1 pair n=256
  if (b < 16) tile_gemm(G + 256*F, F, LI, F, Tw, 256,
                        (b>>2)*64, (b&3)*64, 256, 1.0f, As, Bs);
  gbar(cnt, gen, b, ++bar);
  if (b < 16) tile_gemm(LI + 256*(F+1), F, Tw, 256, LI + 256*F, F,
                        (b>>2)*64, (b&3)*64, 256, -1.0f, As, Bs);
  gbar(cnt, gen, b, ++bar);
  // L4: 512+64, merged
  if (b < 8) {
    tile_gemm(G + 512*F, F, LI, F, Tw, 512, 0, b*64, 512, 1.0f, As, Bs);
    tile_gemm(LI + 512*(F+1), F, Tw, 512, LI + 512*F, F, 0, b*64, 64, -1.0f, As, Bs);
  }
  gbar(cnt, gen, b, ++bar);

  {
    int bg = b >> 2, bo = b & 3;
    tile_gemm(LI, F, Yb, OUTC, Tb, OUTC, bg * 64, bo * 64, bg * 64 + 64, 1.0f, As, Bs);
  }
  gbar(cnt, gen, b, ++bar);

  {
    int bf = b >> 2, bo = b & 3;
    mean_phase(LI, Tb, meanT, bf, bo, As, Bs);
  }
}

// ================= k_gy: G and Y builds merged (z-split) =================
__global__ __launch_bounds__(256) void k_gy(const float* __restrict__ X,
                                            const float* __restrict__ u,
                                            const float* __restrict__ lp,
                                            float* __restrict__ G,
                                            float* __restrict__ Y) {
  __shared__ float As[32][68];
  __shared__ float Bs[32][68];
  int t = threadIdx.x, tx = t & 15, ty = t >> 4;
  if (blockIdx.z == 0) {
    int bi = blockIdx.y, bj = blockIdx.x;
    if (bj > bi) return;
    int f0 = bi * 64, g0 = bj * 64;
    float acc[4][4] = {};
    for (int i0 = 0; i0 < F; i0 += 32) {
      int col = t & 63, kr = t >> 6;
#pragma unroll
      for (int kk = 0; kk < 32; kk += 4) {
        int i = i0 + kr + kk;
        float e = expf(lp[i]);
        As[kr + kk][col] = e * X[i * F + f0 + col];
        Bs[kr + kk][col] = X[i * F + g0 + col];
      }
      __syncthreads();
      mm16(As, Bs, acc, tx, ty);
      __syncthreads();
    }
#pragma unroll
    for (int r = 0; r < 4; ++r) {
      int gr = f0 + ty*4 + r;
#pragma unroll
      for (int c = 0; c < 4; ++c) {
        int gc = g0 + tx*4 + c;
        float v = acc[r][c];
        if (gr == gc) v += PP;
        G[gr * F + gc] = v;
      }
    }
  } else {
    if (blockIdx.x >= 4) return;
    int bo = blockIdx.x, bf = blockIdx.y;
    int f0 = bf * 64, o0 = bo * 64;
    float acc[4][4] = {};
    for (int i0 = 0; i0 < F; i0 += 32) {
      {
        int col = t & 63, kr = t >> 6;
#pragma unroll
        for (int kk = 0; kk < 32; kk += 4) {
          int i = i0 + kr + kk;
          As[kr + kk][col] = expf(lp[i]) * X[i * F + f0 + col];
        }
        int oo = t >> 2, kq = t & 3;
        const float* ur = &u[(o0 + oo) * F + i0 + kq * 8];
        float4 u0 = *(const float4*)ur;
        float4 u1 = *(const float4*)(ur + 4);
        Bs[kq*8+0][oo] = u0.x; Bs[kq*8+1][oo] = u0.y;
        Bs[kq*8+2][oo] = u0.z; Bs[kq*8+3][oo] = u0.w;
        Bs[kq*8+4][oo] = u1.x; Bs[kq*8+5][oo] = u1.y;
        Bs[kq*8+6][oo] = u1.z; Bs[kq*8+7][oo] = u1.w;
      }
      __syncthreads();
      mm16(As, Bs, acc, tx, ty);
      __syncthreads();
    }
#pragma unroll
    for (int r = 0; r < 4; ++r) {
      float4 st = make_float4(acc[r][0], acc[r][1], acc[r][2], acc[r][3]);
      *(float4*)&Y[(f0 + ty*4 + r) * OUTC + o0 + tx*4] = st;
    }
  }
}

// ================= k_split: LIT_H/L[f][g] = split-bf16 of Linv[g][f] =================
__global__ __launch_bounds__(256) void k_split(const float* __restrict__ LI,
                                               u16* __restrict__ H, u16* __restrict__ L) {
  __shared__ float Tt[64][65];
  int gb = blockIdx.x, fb = blockIdx.y;
  int t = threadIdx.x;
  for (int idx = t; idx < 4096; idx += 256) {
    int i = idx >> 6, j = idx & 63;
    Tt[i][j] = LI[(gb * 64 + i) * F + fb * 64 + j];
  }
  __syncthreads();
  for (int idx = t; idx < 4096; idx += 256) {
    int i = idx >> 6, j = idx & 63;
    float x = Tt[j][i];
    u16 h = f2b_rne(x);
    float hf = __uint_as_float((unsigned)h << 16);
    H[(fb * 64 + i) * F + gb * 64 + j] = h;
    L[(fb * 64 + i) * F + gb * 64 + j] = f2b_rne(x - hf);
  }
}

// ================= k_big: MFMA split-bf16 out = Z@Linv + mean, fused f64 partials =================
#define PADK 72
__global__ __launch_bounds__(256) void k_big(const float* __restrict__ Z,
                                             const u16* __restrict__ BHg,
                                             const u16* __restrict__ BLg,
                                             const float* __restrict__ meanT,
                                             float* __restrict__ out,
                                             double* __restrict__ parts) {
  int bf = blockIdx.x, br = blockIdx.y;
  __shared__ u16 ZH[64 * PADK];
  __shared__ u16 ZL[64 * PADK];
  __shared__ u16 BH[64 * PADK];
  __shared__ u16 BL[64 * PADK];
  __shared__ double redA[256];
  __shared__ double redB[256];
  int t = threadIdx.x, l = t & 63, w = t >> 6;
  int f0 = bf * 64, r0 = br * 64;
  int rr = t >> 2, kq = t & 3;
  f32x4 acc0 = {0.f,0.f,0.f,0.f}, acc1 = {0.f,0.f,0.f,0.f};
  f32x4 acc2 = {0.f,0.f,0.f,0.f}, acc3 = {0.f,0.f,0.f,0.f};
  double zsq = 0.0;

  for (int g0 = f0; g0 < F; g0 += 64) {
    {
      const float* zp = &Z[(r0 + rr) * F + g0 + kq * 16];
      float xs[16];
      *(float4*)&xs[0]  = *(const float4*)(zp + 0);
      *(float4*)&xs[4]  = *(const float4*)(zp + 4);
      *(float4*)&xs[8]  = *(const float4*)(zp + 8);
      *(float4*)&xs[12] = *(const float4*)(zp + 12);
      u16 hh[16], ll[16];
#pragma unroll
      for (int j = 0; j < 16; ++j) {
        u16 h = f2b_rne(xs[j]);
        float hf = __uint_as_float((unsigned)h << 16);
        hh[j] = h;
        ll[j] = f2b_rne(xs[j] - hf);
        if (bf == 0) zsq += (double)xs[j] * xs[j];
      }
      *(short8*)&ZH[rr * PADK + kq * 16 + 0] = *(short8*)&hh[0];
      *(short8*)&ZH[rr * PADK + kq * 16 + 8] = *(short8*)&hh[8];
      *(short8*)&ZL[rr * PADK + kq * 16 + 0] = *(short8*)&ll[0];
      *(short8*)&ZL[rr * PADK + kq * 16 + 8] = *(short8*)&ll[8];
      const u16* bh = &BHg[(f0 + rr) * F + g0 + kq * 16];
      const u16* bl = &BLg[(f0 + rr) * F + g0 + kq * 16];
      *(short8*)&BH[rr * PADK + kq * 16 + 0] = *(const short8*)(bh + 0);
      *(short8*)&BH[rr * PADK + kq * 16 + 8] = *(const short8*)(bh + 8);
      *(short8*)&BL[rr * PADK + kq * 16 + 0] = *(const short8*)(bl + 0);
      *(short8*)&BL[rr * PADK + kq * 16 + 8] = *(const short8*)(bl + 8);
    }
    __syncthreads();
#pragma unroll
    for (int kk = 0; kk < 2; ++kk) {
      int aoff = (w * 16 + (l & 15)) * PADK + kk * 32 + (l >> 4) * 8;
      short8 ah = *(short8*)&ZH[aoff];
      short8 al = *(short8*)&ZL[aoff];
      int b0o = ((l & 15)) * PADK + kk * 32 + (l >> 4) * 8;
      {
        short8 bh = *(short8*)&BH[b0o];
        short8 bl = *(short8*)&BL[b0o];
        acc0 = __builtin_amdgcn_mfma_f32_16x16x32_bf16(ah, bh, acc0, 0, 0, 0);
        acc0 = __builtin_amdgcn_mfma_f32_16x16x32_bf16(ah, bl, acc0, 0, 0, 0);
        acc0 = __builtin_amdgcn_mfma_f32_16x16x32_bf16(al, bh, acc0, 0, 0, 0);
      }
      {
        short8 bh = *(short8*)&BH[b0o + 16 * PADK];
        short8 bl = *(short8*)&BL[b0o + 16 * PADK];
        acc1 = __builtin_amdgcn_mfma_f32_16x16x32_bf16(ah, bh, acc1, 0, 0, 0);
        acc1 = __builtin_amdgcn_mfma_f32_16x16x32_bf16(ah, bl, acc1, 0, 0, 0);
        acc1 = __builtin_amdgcn_mfma_f32_16x16x32_bf16(al, bh, acc1, 0, 0, 0);
      }
      {
        short8 bh = *(short8*)&BH[b0o + 32 * PADK];
        short8 bl = *(short8*)&BL[b0o + 32 * PADK];
        acc2 = __builtin_amdgcn_mfma_f32_16x16x32_bf16(ah, bh, acc2, 0, 0, 0);
        acc2 = __builtin_amdgcn_mfma_f32_16x16x32_bf16(ah, bl, acc2, 0, 0, 0);
        acc2 = __builtin_amdgcn_mfma_f32_16x16x32_bf16(al, bh, acc2, 0, 0, 0);
      }
      {
        short8 bh = *(short8*)&BH[b0o + 48 * PADK];
        short8 bl = *(short8*)&BL[b0o + 48 * PADK];
        acc3 = __builtin_amdgcn_mfma_f32_16x16x32_bf16(ah, bh, acc3, 0, 0, 0);
        acc3 = __builtin_amdgcn_mfma_f32_16x16x32_bf16(ah, bl, acc3, 0, 0, 0);
        acc3 = __builtin_amdgcn_mfma_f32_16x16x32_bf16(al, bh, acc3, 0, 0, 0);
      }
    }
    __syncthreads();
  }

  double ssq = 0.0;
  int colb = l & 15, rq = l >> 4;
#pragma unroll
  for (int c = 0; c < 4; ++c) {
    f32x4 a = (c == 0) ? acc0 : (c == 1) ? acc1 : (c == 2) ? acc2 : acc3;
#pragma unroll
    for (int r = 0; r < 4; ++r) {
      int row = r0 + w * 16 + rq * 4 + r;
      int col = f0 + c * 16 + colb;
      float v = a[r] + meanT[(row & 255) * F + col];
      out[row * F + col] = v;
      ssq += (double)v * v;
    }
  }
  redA[t] = ssq; redB[t] = zsq;
  __syncthreads();
  for (int o = 128; o > 0; o >>= 1) {
    if (t < o) { redA[t] += redA[t + o]; redB[t] += redB[t + o]; }
    __syncthreads();
  }
  if (t == 0) {
    int s = br >> 2;
    atomicAdd(&parts[s * 2 + 0], redA[0]);
    if (bf == 0) atomicAdd(&parts[s * 2 + 1], redB[0]);
  }
}

// ================= logpq final =================
__global__ __launch_bounds__(576) void k_logpq_final(const float* __restrict__ LI,
                                                     const double* __restrict__ parts,
                                                     float* __restrict__ out) {
  __shared__ double red[576];
  int t = threadIdx.x;
  red[t] = log((double)LI[t * F + t]);   // = -log(L[t][t])
  __syncthreads();
  for (int o = 512; o > 0; o >>= 1) {
    if (t < o && t + o < 576) red[t] += red[t + o];
    __syncthreads();
  }
  double ldsumLI = red[0];
  if (t < SNUM) {
    double ssq = parts[t * 2 + 0];
    double zsq = parts[t * 2 + 1];
    double pp = 576.0;
    double lpq = -0.5 * pp * ssq
               + 0.5 * (double)(OUTC * F) * log(pp)
               + 0.5 * zsq
               + (double)OUTC * ldsumLI;
    out[SNUM * OUTC * F + t] = (float)lpq;
  }
}

// ================= launch =================
extern "C" void kernel_launch(void* const* d_in, const int* in_sizes, int n_in,
                              void* d_out, int out_size, void* d_ws, size_t ws_size,
                              hipStream_t stream) {
  (void)in_sizes; (void)n_in; (void)out_size; (void)ws_size;
  const float* X  = (const float*)d_in[1];   // Xi_param [1,576,576]
  const float* u  = (const float*)d_in[2];   // u [256,576,1]
  const float* lp = (const float*)d_in[3];   // log_prec_scaled [1,1,576]
  const float* Z  = (const float*)d_in[4];   // Z [64,256,576,1]
  float* out = (float*)d_out;

  float* ws    = (float*)d_ws;
  float* G     = ws;                   // 331776 (L factor; reused as LIT after k_mid)
  float* LI    = ws + 331776;          // 331776
  float* Yb    = ws + 663552;          // 147456
  float* Tb    = ws + 811008;          // 147456 (also trigemm temp)
  float* meanT = ws + 958464;          // 147456
  double* parts = (double*)(ws + 1105920);        // 128 doubles (1024 B)
  int*    cnt   = (int*)(ws + 1105920 + 256);     // arrival counter (own line)
  int*    gen   = (int*)(ws + 1105920 + 288);     // publish word (separate line)
  u16* LIT_H = (u16*)G;                // 331776 u16 (overwrites G after k_mid)
  u16* LIT_L = LIT_H + 331776;         // 331776 u16

  hipMemsetAsync((void*)(ws + 1105920), 0, 1416, stream);  // parts + cnt + gen
  k_gy<<<dim3(9, 9, 2), 256, 0, stream>>>(X, u, lp, G, Yb);
  k_mid<<<NBLK, 256, 0, stream>>>(G, LI, Yb, Tb, meanT, cnt, gen);
  k_split<<<dim3(9, 9), 256, 0, stream>>>(LI, LIT_H, LIT_L);
  k_big<<<dim3(9, 256), 256, 0, stream>>>(Z, LIT_H, LIT_L, meanT, out, parts);
  k_logpq_final<<<1, 576, 0, stream>>>(LI, parts, out);
}